// Round 15
// baseline (1502.834 us; speedup 1.0000x reference)
//
#include <hip/hip_runtime.h>

// ---------------- types & helpers ----------------
typedef short short8 __attribute__((ext_vector_type(8)));
typedef float f32x4 __attribute__((ext_vector_type(4)));
typedef unsigned short u16x4 __attribute__((ext_vector_type(4)));

#define MFMA_BF16(a, b, c) __builtin_amdgcn_mfma_f32_16x16x32_bf16((a), (b), (c), 0, 0, 0)
#define PIN_AGPR(x) asm volatile("" : "+a"(x))

// async global->LDS, 16B per lane (vmcnt-tracked, NO VGPR destination).
__device__ __forceinline__ void gload_lds16(const void* g, void* l) {
    __builtin_amdgcn_global_load_lds(
        (const __attribute__((address_space(1))) unsigned int*)g,
        (__attribute__((address_space(3))) unsigned int*)l, 16, 0, 0);
}

__device__ __forceinline__ float bf2f(unsigned short u) {
    return __uint_as_float(((unsigned)u) << 16);
}
__device__ __forceinline__ unsigned short f2bf(float f) {
    unsigned u = __float_as_uint(f);
    u += 0x7FFFu + ((u >> 16) & 1u);  // round-to-nearest-even
    return (unsigned short)(u >> 16);
}
// rcp-based (v_rcp_f32, ~1ulp) — full-precision divides were 38.9% VALUBusy in r14.
__device__ __forceinline__ float sigm(float x) {
    return __builtin_amdgcn_rcpf(1.0f + __expf(-x));
}
__device__ __forceinline__ float tanh_(float x) {
    float e = __expf(-2.0f * fabsf(x));
    float t = (1.0f - e) * __builtin_amdgcn_rcpf(1.0f + e);
    return copysignf(t, x);
}

#define TT 30

// ---------------- weight conversion / packing ----------------
// Regions: Whid_b 65536 | Wih0_b 262144 | Wp0 262144 (frag-packed W_hh0) |
//   Wp1 524288 (frag-packed [W_ih1|W_hh1]) | biasC 1024
__global__ __launch_bounds__(256) void cvt_weights(
    const float* __restrict__ W_hid, const float* __restrict__ W_ih0,
    const float* __restrict__ W_hh0, const float* __restrict__ W_ih1,
    const float* __restrict__ W_hh1, const float* __restrict__ b_ih1,
    const float* __restrict__ b_hh1,
    unsigned short* __restrict__ Whid_b, unsigned short* __restrict__ Wih0_b,
    unsigned short* __restrict__ Wp0, unsigned short* __restrict__ Wp1,
    float* __restrict__ biasC)
{
    int idx = blockIdx.x * 256 + threadIdx.x;
    if (idx < 65536) { Whid_b[idx] = f2bf(W_hid[idx]); return; }
    idx -= 65536;
    if (idx < 262144) {
        int gc = idx >> 8, k = idx & 255;
        Wih0_b[idx] = f2bf(W_ih0[gc * 258 + k]);
        return;
    }
    idx -= 262144;
    if (idx < 262144) {
        int p = idx;
        int e = p & 7, L = (p >> 3) & 63, kbi = (p >> 9) & 7, n = p >> 12;
        int h16 = n >> 2, g = n & 3;
        int j = g * 256 + h16 * 16 + (L & 15);
        int k = kbi * 32 + (L >> 4) * 8 + e;
        Wp0[p] = f2bf(W_hh0[j * 256 + k]);
        return;
    }
    idx -= 262144;
    if (idx < 524288) {
        int p = idx;
        int e = p & 7, L = (p >> 3) & 63, kbi = (p >> 9) & 15, n = p >> 13;
        int h16 = n >> 2, g = n & 3;
        int j = g * 256 + h16 * 16 + (L & 15);
        int k = kbi * 32 + (L >> 4) * 8 + e;
        float v = (k < 256) ? W_ih1[j * 256 + k] : W_hh1[j * 256 + (k - 256)];
        Wp1[p] = f2bf(v);
        return;
    }
    idx -= 524288;
    if (idx < 1024) biasC[idx] = b_ih1[idx] + b_hh1[idx];
}

// ---------------- pack the per-wave SEQUENTIAL stream Wcomb ----------------
// Wcomb[w][s][g2][L][e]: sub-chunk s (0..95) = 2 gate-slices of 512 ushorts.
//  s<32  (phase A): half=s>>4, kbi=(s>>1)&7, gp=s&1, n=half*4+gp*2+g2 -> Wp0
//  s>=32 (phase B): t=s-32: half=t>>5, kk=(t>>1)&15, gp=t&1           -> Wp1
__global__ __launch_bounds__(256) void pack_comb(
    const unsigned short* __restrict__ Wp0, const unsigned short* __restrict__ Wp1,
    unsigned short* __restrict__ Wcomb)
{
    int idx = blockIdx.x * 256 + threadIdx.x;   // < 786432
    int w = idx / 98304;
    int r = idx - w * 98304;
    int s = r >> 10;
    int q = r & 1023;
    int g2 = q >> 9;
    int le = q & 511;
    unsigned short v;
    if (s < 32) {
        int half = s >> 4, kbi = (s >> 1) & 7, gp = s & 1;
        int nl = half * 4 + gp * 2 + g2;
        v = Wp0[(size_t)(w * 8 + nl) * 4096 + kbi * 512 + le];
    } else {
        int t = s - 32;
        int half = t >> 5, kk = (t >> 1) & 15, gp = t & 1;
        int nl = half * 4 + gp * 2 + g2;
        v = Wp1[(size_t)(w * 8 + nl) * 8192 + kk * 512 + le];
    }
    Wcomb[idx] = v;
}

// combined[n, c] : c<128 obs[b], c<192 lane[b], else ds[kk]
__global__ __launch_bounds__(256) void build_combined(
    const float* __restrict__ obs, const float* __restrict__ lane,
    const float* __restrict__ ds, unsigned short* __restrict__ comb)
{
    int idx = blockIdx.x * 256 + threadIdx.x;  // < 6144*256
    int n = idx >> 8, c = idx & 255;
    int b = n / 6, kk = n - b * 6;
    float v;
    if (c < 128)      v = obs[b * 128 + c];
    else if (c < 192) v = lane[b * 64 + (c - 128)];
    else              v = ds[kk * 64 + (c - 192)];
    comb[idx] = f2bf(v);
}

// ---------------- GEMM: hidden = leakyrelu(combined @ W_hid^T + b_hid) ----------------
__global__ __launch_bounds__(256) void gemm_hidden(
    const unsigned short* __restrict__ A, const unsigned short* __restrict__ B,
    const float* __restrict__ b_hid, unsigned short* __restrict__ hidden)
{
    int wid = threadIdx.x >> 6, lane = threadIdx.x & 63;
    int lrow = lane & 15, kg = lane >> 4;
    int r0 = blockIdx.x * 64;
    int c0 = wid * 64;
    f32x4 acc[4][4];
#pragma unroll
    for (int i = 0; i < 4; i++)
#pragma unroll
        for (int j = 0; j < 4; j++) acc[i][j] = f32x4{0.f, 0.f, 0.f, 0.f};

#pragma unroll
    for (int kb = 0; kb < 256; kb += 32) {
        int k = kb + kg * 8;
        short8 a[4], b[4];
#pragma unroll
        for (int mi = 0; mi < 4; mi++)
            a[mi] = *(const short8*)(A + (size_t)(r0 + mi * 16 + lrow) * 256 + k);
#pragma unroll
        for (int ni = 0; ni < 4; ni++)
            b[ni] = *(const short8*)(B + (size_t)(c0 + ni * 16 + lrow) * 256 + k);
#pragma unroll
        for (int mi = 0; mi < 4; mi++)
#pragma unroll
            for (int ni = 0; ni < 4; ni++)
                acc[mi][ni] = MFMA_BF16(a[mi], b[ni], acc[mi][ni]);
    }
#pragma unroll
    for (int mi = 0; mi < 4; mi++) {
#pragma unroll
        for (int ni = 0; ni < 4; ni++) {
            int col = c0 + ni * 16 + lrow;
            float bb = b_hid[col];
#pragma unroll
            for (int r = 0; r < 4; r++) {
                int row = r0 + mi * 16 + kg * 4 + r;
                float x = acc[mi][ni][r] + bb;
                x = x >= 0.f ? x : 0.1f * x;
                hidden[(size_t)row * 256 + col] = f2bf(x);
            }
        }
    }
}

// ---------------- endpoint / conf head (thread per row) ----------------
__global__ __launch_bounds__(256) void head_kernel(
    const unsigned short* __restrict__ hidden, const float* __restrict__ W_ep,
    const float* __restrict__ b_ep, const float* __restrict__ W_conf,
    const float* __restrict__ b_conf, float* __restrict__ out_conf,
    float* __restrict__ out_ep, float* __restrict__ ep_buf)
{
    int n = blockIdx.x * 256 + threadIdx.x;  // < 6144
    const unsigned short* hr = hidden + (size_t)n * 256;
    float e0 = 0.f, e1 = 0.f, cf = 0.f;
    for (int k = 0; k < 256; k += 8) {
        short8 hv = *(const short8*)(hr + k);
#pragma unroll
        for (int i = 0; i < 8; i++) {
            float h = bf2f((unsigned short)hv[i]);
            e0 += h * W_ep[k + i];
            e1 += h * W_ep[256 + k + i];
            cf += h * W_conf[k + i];
        }
    }
    e0 += b_ep[0]; e1 += b_ep[1]; cf += b_conf[0];
    out_conf[n] = cf;
    out_ep[2 * n] = e0; out_ep[2 * n + 1] = e1;
    ep_buf[2 * n] = e0; ep_buf[2 * n + 1] = e1;
}

// ---------------- GEMM: gx0 (b_ih0+b_hh0 folded, ep rank-2), bf16 frag-layout out ----
__global__ __launch_bounds__(256) void gemm_gx0(
    const unsigned short* __restrict__ A, const unsigned short* __restrict__ B,
    const float* __restrict__ W_ih0f, const float* __restrict__ b_ih0,
    const float* __restrict__ b_hh0, const float* __restrict__ ep_buf,
    u16x4* __restrict__ gxs4)
{
    int wid = threadIdx.x >> 6, lane = threadIdx.x & 63;
    int lrow = lane & 15, kg = lane >> 4;
    int r0 = blockIdx.x * 64;
    int g  = blockIdx.y;                   // gate
    int c0 = g * 256 + wid * 64;
    f32x4 acc[4][4];
#pragma unroll
    for (int i = 0; i < 4; i++)
#pragma unroll
        for (int j = 0; j < 4; j++) acc[i][j] = f32x4{0.f, 0.f, 0.f, 0.f};

#pragma unroll
    for (int kb = 0; kb < 256; kb += 32) {
        int k = kb + kg * 8;
        short8 a[4], b[4];
#pragma unroll
        for (int mi = 0; mi < 4; mi++)
            a[mi] = *(const short8*)(A + (size_t)(r0 + mi * 16 + lrow) * 256 + k);
#pragma unroll
        for (int ni = 0; ni < 4; ni++)
            b[ni] = *(const short8*)(B + (size_t)(c0 + ni * 16 + lrow) * 256 + k);
#pragma unroll
        for (int mi = 0; mi < 4; mi++)
#pragma unroll
            for (int ni = 0; ni < 4; ni++)
                acc[mi][ni] = MFMA_BF16(a[mi], b[ni], acc[mi][ni]);
    }
#pragma unroll
    for (int mi = 0; mi < 4; mi++) {
#pragma unroll
        for (int ni = 0; ni < 4; ni++) {
            int gc = c0 + ni * 16 + lrow;
            float w256 = W_ih0f[(size_t)gc * 258 + 256];
            float w257 = W_ih0f[(size_t)gc * 258 + 257];
            float bb = b_ih0[gc] + b_hh0[gc];
            int h16 = wid * 4 + ni;
            int wv = h16 >> 1, ni2 = h16 & 1;
            int pb = blockIdx.x * 2 + (mi >> 1);
            int idx16 = ((mi & 1) * 2 + ni2) * 4 + g;
            u16x4 pv;
#pragma unroll
            for (int r = 0; r < 4; r++) {
                int row = r0 + mi * 16 + kg * 4 + r;
                float v = acc[mi][ni][r] + bb + ep_buf[2 * row] * w256 + ep_buf[2 * row + 1] * w257;
                pv[r] = f2bf(v);
            }
            gxs4[(size_t)((pb * 8 + wv) * 16 + idx16) * 64 + lane] = pv;
        }
    }
}

// ---------------- persistent 30-step LSTM: counted-vmcnt weight stream --------
// 192 blocks x 512 threads (8 waves). Block owns 32 rows. Wave w: hcols [w*32,+32).
// Weights stream global->LDS as ONE sequential 96x2KB-chunk stream per iter
// (Wcomb), 5-buffer ring, 4 chunks ahead, s_waitcnt vmcnt(6) steady (T4).
// In-flight weights use ZERO VGPRs. Epilogue transcendentals use v_rcp_f32
// (r14: full-precision divides were 38.9% VALUBusy).
// LDS 146KB: h0 pp @0/16KB, h1 pp @32/48KB (XOR swizzle col^((row&7)<<3)),
// ring bufs @64KB+w*10KB, W_op copy @144KB. gx in 16 regs; c AGPR-pinned;
// biasL1 in 8 regs; NO other vmem in hot loop (counted waits stay valid).
#define STG(sv)                                                              \
    {                                                                        \
        const unsigned short* _s = wc + (size_t)(sv) * 1024;                 \
        unsigned short* _d = wbuf_base + ((sv) % 5) * 1024;                  \
        gload_lds16(_s, _d);                                                 \
        gload_lds16(_s + 512, _d + 512);                                     \
    }

#define EPIA(HALF)                                                           \
    {                                                                        \
        int col = w * 32 + (HALF) * 16 + lrow;                               \
        _Pragma("unroll") for (int mi = 0; mi < 2; mi++) {                   \
            u16x4 gI = gxr[(mi * 2 + (HALF)) * 4 + 0];                       \
            u16x4 gF = gxr[(mi * 2 + (HALF)) * 4 + 1];                       \
            u16x4 gG = gxr[(mi * 2 + (HALF)) * 4 + 2];                       \
            u16x4 gO = gxr[(mi * 2 + (HALF)) * 4 + 3];                       \
            f32x4 cp = c0r[mi][(HALF)];                                      \
            f32x4 cnv;                                                       \
            _Pragma("unroll") for (int r = 0; r < 4; r++) {                  \
                float gi = acc[mi][0][r] + bf2f(gI[r]);                      \
                float gf = acc[mi][1][r] + bf2f(gF[r]);                      \
                float gg = acc[mi][2][r] + bf2f(gG[r]);                      \
                float go = acc[mi][3][r] + bf2f(gO[r]);                      \
                float cn = sigm(gf) * cp[r] + sigm(gi) * tanh_(gg);          \
                float hn = sigm(go) * tanh_(cn);                             \
                cnv[r] = cn;                                                 \
                int row = mi * 16 + kg * 4 + r;                              \
                h0new[row * 256 + (col ^ ((row & 7) << 3))] = f2bf(hn);      \
            }                                                                \
            c0r[mi][(HALF)] = cnv;                                           \
            PIN_AGPR(c0r[mi][(HALF)]);                                       \
            _Pragma("unroll") for (int g = 0; g < 4; g++)                    \
                acc[mi][g] = f32x4{0.f, 0.f, 0.f, 0.f};                      \
        }                                                                    \
    }

#define EPIB(HALF)                                                           \
    {                                                                        \
        int col = w * 32 + (HALF) * 16 + lrow;                               \
        _Pragma("unroll") for (int mi = 0; mi < 2; mi++) {                   \
            f32x4 cp = c1r[mi][(HALF)];                                      \
            f32x4 cnv;                                                       \
            _Pragma("unroll") for (int r = 0; r < 4; r++) {                  \
                float gi = acc[mi][0][r] + biasL1[(HALF) * 4 + 0];           \
                float gf = acc[mi][1][r] + biasL1[(HALF) * 4 + 1];           \
                float gg = acc[mi][2][r] + biasL1[(HALF) * 4 + 2];           \
                float go = acc[mi][3][r] + biasL1[(HALF) * 4 + 3];           \
                float cn = sigm(gf) * cp[r] + sigm(gi) * tanh_(gg);          \
                float hn = sigm(go) * tanh_(cn);                             \
                cnv[r] = cn;                                                 \
                int row = mi * 16 + kg * 4 + r;                              \
                h1new[row * 256 + (col ^ ((row & 7) << 3))] = f2bf(hn);      \
            }                                                                \
            c1r[mi][(HALF)] = cnv;                                           \
            PIN_AGPR(c1r[mi][(HALF)]);                                       \
            _Pragma("unroll") for (int g = 0; g < 4; g++)                    \
                acc[mi][g] = f32x4{0.f, 0.f, 0.f, 0.f};                      \
        }                                                                    \
    }

__global__ __launch_bounds__(512, 1) void lstm_persistent(
    const unsigned short* __restrict__ Wp0, const unsigned short* __restrict__ Wp1,
    const unsigned short* __restrict__ Wcomb,
    const u16x4* __restrict__ gxs4, const float* __restrict__ biasC,
    const float* __restrict__ W_op, const float* __restrict__ b_op,
    float* __restrict__ out_final)
{
    __shared__ unsigned short lds[74752];   // 146 KB

    const int blk  = blockIdx.x;            // rows blk*32 .. +32
    const int w    = threadIdx.x >> 6;
    const int lane = threadIdx.x & 63;
    const int lrow = lane & 15;
    const int kg   = lane >> 4;
    const int sw   = (lrow & 7) << 3;       // A-frag k-swizzle

    // W_op copy into LDS (keeps proj off vmcnt in the hot loop)
    float* wopl = (float*)&lds[73728];
    wopl[threadIdx.x] = W_op[threadIdx.x];

    // gx preload into registers — 16 VGPR
    u16x4 gxr[16];
    {
        const u16x4* gxw = gxs4 + (size_t)(blk * 8 + w) * 16 * 64;
#pragma unroll
        for (int j = 0; j < 16; j++) gxr[j] = gxw[j * 64 + lane];
    }
    // L1 biases in 8 regs (keeps them off vmcnt in the hot loop)
    float biasL1[8];
#pragma unroll
    for (int ni2 = 0; ni2 < 2; ni2++)
#pragma unroll
        for (int g = 0; g < 4; g++)
            biasL1[ni2 * 4 + g] = biasC[g * 256 + w * 32 + ni2 * 16 + lrow];

    f32x4 c0r[2][2], c1r[2][2];
#pragma unroll
    for (int mi = 0; mi < 2; mi++)
#pragma unroll
        for (int ni2 = 0; ni2 < 2; ni2++) {
            c0r[mi][ni2] = f32x4{0.f, 0.f, 0.f, 0.f};
            c1r[mi][ni2] = f32x4{0.f, 0.f, 0.f, 0.f};
            PIN_AGPR(c0r[mi][ni2]);
            PIN_AGPR(c1r[mi][ni2]);
        }

    const unsigned short* wc = Wcomb + (size_t)w * 98304 + (size_t)lane * 8;
    unsigned short* wbuf_base = &lds[32768 + w * 5120];        // wave-uniform dest
    const unsigned short* wbufL = wbuf_base + lane * 8;        // per-lane read
    const unsigned short* wp0w = Wp0 + (size_t)w * 32768 + (size_t)lane * 8;
    const unsigned short* wp1w = Wp1 + (size_t)w * 65536 + (size_t)lane * 8;

    const int prow = threadIdx.x >> 4;
    const int pseg = threadIdx.x & 15;
    const int psw  = (prow & 7) << 3;

    f32x4 acc[2][4];
#pragma unroll
    for (int mi = 0; mi < 2; mi++)
#pragma unroll
        for (int g = 0; g < 4; g++) acc[mi][g] = f32x4{0.f, 0.f, 0.f, 0.f};

    // ================= i = 0 : h0[0] from gx only =================
    {
        unsigned short* h0new = lds;  // buffer 0
        EPIA(0);
        EPIA(1);
    }
    __syncthreads();

    // ================= i = 1 : direct A + direct B-init =================
    {
        unsigned short* h0new = lds + 8192;       // h0[1]
        const unsigned short* h0prev = lds;       // h0[0]
#pragma unroll
        for (int half = 0; half < 2; half++) {
#pragma unroll
            for (int kbi = 0; kbi < 8; kbi++) {
                short8 a0, a1, b[4];
                int k = (kbi * 32 + kg * 8) ^ sw;
                a0 = *(const short8*)&h0prev[lrow * 256 + k];
                a1 = *(const short8*)&h0prev[(16 + lrow) * 256 + k];
#pragma unroll
                for (int g = 0; g < 4; g++)
                    b[g] = *(const short8*)&wp0w[(size_t)(((half * 4 + g) * 8 + kbi) * 512)];
#pragma unroll
                for (int g = 0; g < 4; g++) {
                    acc[0][g] = MFMA_BF16(a0, b[g], acc[0][g]);
                    acc[1][g] = MFMA_BF16(a1, b[g], acc[1][g]);
                }
            }
            if (half == 0) { EPIA(0); } else { EPIA(1); }
        }
        // B-init: h1[0], c1 = i-gate * g-gate only
        unsigned short* h1new = lds + 16384;      // h1[0] -> ping 0
#pragma unroll
        for (int half = 0; half < 2; half++) {
#pragma unroll
            for (int kbi = 0; kbi < 8; kbi++) {
                short8 a0, a1, b[4];
                int k = (kbi * 32 + kg * 8) ^ sw;
                a0 = *(const short8*)&h0prev[lrow * 256 + k];
                a1 = *(const short8*)&h0prev[(16 + lrow) * 256 + k];
#pragma unroll
                for (int g = 0; g < 4; g++)
                    b[g] = *(const short8*)&wp1w[(size_t)(((half * 4 + g) * 16 + kbi) * 512)];
#pragma unroll
                for (int g = 0; g < 4; g++) {
                    acc[0][g] = MFMA_BF16(a0, b[g], acc[0][g]);
                    acc[1][g] = MFMA_BF16(a1, b[g], acc[1][g]);
                }
            }
            int col = w * 32 + half * 16 + lrow;
#pragma unroll
            for (int mi = 0; mi < 2; mi++) {
                f32x4 cnv;
#pragma unroll
                for (int r = 0; r < 4; r++) {
                    float gi = acc[mi][0][r] + biasL1[half * 4 + 0];
                    float gg = acc[mi][2][r] + biasL1[half * 4 + 2];
                    float go = acc[mi][3][r] + biasL1[half * 4 + 3];
                    float cn = sigm(gi) * tanh_(gg);
                    float hn = sigm(go) * tanh_(cn);
                    cnv[r] = cn;
                    int row = mi * 16 + kg * 4 + r;
                    h1new[row * 256 + (col ^ ((row & 7) << 3))] = f2bf(hn);
                }
                c1r[mi][half] = cnv;
                PIN_AGPR(c1r[mi][half]);
#pragma unroll
                for (int g = 0; g < 4; g++) acc[mi][g] = f32x4{0.f, 0.f, 0.f, 0.f};
            }
        }
    }
    __syncthreads();

    // ================= i = 2..29 : streamed full iterations =================
    for (int i = 2; i <= 29; ++i) {
        unsigned short* h0new = lds + (i & 1) * 8192;
        const unsigned short* h0prev = lds + ((i - 1) & 1) * 8192;
        const unsigned short* h1prev = lds + 16384 + (i & 1) * 8192;
        unsigned short* h1new = lds + 16384 + ((i - 1) & 1) * 8192;

        STG(0); STG(1); STG(2); STG(3);

        short8 a0, a1;
        // ---- phase A: chunks 0..31 ----
#pragma unroll
        for (int s = 0; s < 32; s++) {
            const int kbi = (s >> 1) & 7;
            const int g0 = (s & 1) * 2;
            if ((s & 1) == 0) {
                int k = (kbi * 32 + kg * 8) ^ sw;
                a0 = *(const short8*)&h0prev[lrow * 256 + k];
                a1 = *(const short8*)&h0prev[(16 + lrow) * 256 + k];
            }
            asm volatile("s_waitcnt vmcnt(6)" ::: "memory");
            short8 b0 = *(const short8*)(wbufL + (s % 5) * 1024);
            short8 b1 = *(const short8*)(wbufL + (s % 5) * 1024 + 512);
            acc[0][g0]     = MFMA_BF16(a0, b0, acc[0][g0]);
            acc[1][g0]     = MFMA_BF16(a1, b0, acc[1][g0]);
            acc[0][g0 + 1] = MFMA_BF16(a0, b1, acc[0][g0 + 1]);
            acc[1][g0 + 1] = MFMA_BF16(a1, b1, acc[1][g0 + 1]);
            STG(s + 4);
            if (s == 15) { EPIA(0); }
        }
        EPIA(1);

        // ---- phase B: chunks 32..95 ----
#pragma unroll
        for (int s = 32; s < 96; s++) {
            const int t = s - 32;
            const int kk = (t >> 1) & 15;
            const int g0 = (t & 1) * 2;
            if ((t & 1) == 0) {
                const unsigned short* hsrc = (kk < 8) ? h0prev : h1prev;
                int k = ((kk & 7) * 32 + kg * 8) ^ sw;
                a0 = *(const short8*)&hsrc[lrow * 256 + k];
                a1 = *(const short8*)&hsrc[(16 + lrow) * 256 + k];
            }
            if (s <= 92)      asm volatile("s_waitcnt vmcnt(6)" ::: "memory");
            else if (s == 93) asm volatile("s_waitcnt vmcnt(4)" ::: "memory");
            else if (s == 94) asm volatile("s_waitcnt vmcnt(2)" ::: "memory");
            else              asm volatile("s_waitcnt vmcnt(0)" ::: "memory");
            short8 b0 = *(const short8*)(wbufL + (s % 5) * 1024);
            short8 b1 = *(const short8*)(wbufL + (s % 5) * 1024 + 512);
            acc[0][g0]     = MFMA_BF16(a0, b0, acc[0][g0]);
            acc[1][g0]     = MFMA_BF16(a1, b0, acc[1][g0]);
            acc[0][g0 + 1] = MFMA_BF16(a0, b1, acc[0][g0 + 1]);
            acc[1][g0 + 1] = MFMA_BF16(a1, b1, acc[1][g0 + 1]);
            if (s + 4 < 96) STG(s + 4);
            if (t == 31) { EPIB(0); }
        }
        EPIB(1);

        // ---- out-projection: t = i-2 (reads h1[i-2]) ----
        {
            const unsigned short* h1t = lds + 16384 + (i & 1) * 8192;
            float p0 = 0.f, p1 = 0.f;
#pragma unroll
            for (int q = 0; q < 2; q++) {
                int col0 = pseg * 16 + q * 8;
                short8 hv = *(const short8*)&h1t[prow * 256 + (col0 ^ psw)];
#pragma unroll
                for (int e = 0; e < 8; e++) {
                    float h = bf2f((unsigned short)hv[e]);
                    p0 += h * wopl[col0 + e];
                    p1 += h * wopl[256 + col0 + e];
                }
            }
#pragma unroll
            for (int sfl = 1; sfl < 16; sfl <<= 1) {
                p0 += __shfl_xor(p0, sfl, 64);
                p1 += __shfl_xor(p1, sfl, 64);
            }
            if (pseg == 0) {
                int grow = blk * 32 + prow;
                int t = i - 2;
                out_final[((size_t)grow * TT + t) * 2 + 0] = p0 + b_op[0];
                out_final[((size_t)grow * TT + t) * 2 + 1] = p1 + b_op[1];
            }
        }
        __syncthreads();
    }

    // ================= i = 30 : direct B + proj(28) =================
    {
        const int i = 30;
        const unsigned short* h0prev = lds + ((i - 1) & 1) * 8192;
        const unsigned short* h1prev = lds + 16384 + (i & 1) * 8192;
        unsigned short* h1new = lds + 16384 + ((i - 1) & 1) * 8192;
#pragma unroll
        for (int half = 0; half < 2; half++) {
#pragma unroll
            for (int kk = 0; kk < 16; kk++) {
                short8 a0, a1, b[4];
                const unsigned short* hsrc = (kk < 8) ? h0prev : h1prev;
                int k = ((kk & 7) * 32 + kg * 8) ^ sw;
                a0 = *(const short8*)&hsrc[lrow * 256 + k];
                a1 = *(const short8*)&hsrc[(16 + lrow) * 256 + k];
#pragma unroll
                for (int g = 0; g < 4; g++)
                    b[g] = *(const short8*)&wp1w[(size_t)(((half * 4 + g) * 16 + kk) * 512)];
#pragma unroll
                for (int g = 0; g < 4; g++) {
                    acc[0][g] = MFMA_BF16(a0, b[g], acc[0][g]);
                    acc[1][g] = MFMA_BF16(a1, b[g], acc[1][g]);
                }
            }
            if (half == 0) { EPIB(0); } else { EPIB(1); }
        }
        {
            const unsigned short* h1t = lds + 16384 + (i & 1) * 8192;
            float p0 = 0.f, p1 = 0.f;
#pragma unroll
            for (int q = 0; q < 2; q++) {
                int col0 = pseg * 16 + q * 8;
                short8 hv = *(const short8*)&h1t[prow * 256 + (col0 ^ psw)];
#pragma unroll
                for (int e = 0; e < 8; e++) {
                    float h = bf2f((unsigned short)hv[e]);
                    p0 += h * wopl[col0 + e];
                    p1 += h * wopl[256 + col0 + e];
                }
            }
#pragma unroll
            for (int sfl = 1; sfl < 16; sfl <<= 1) {
                p0 += __shfl_xor(p0, sfl, 64);
                p1 += __shfl_xor(p1, sfl, 64);
            }
            if (pseg == 0) {
                int grow = blk * 32 + prow;
                out_final[((size_t)grow * TT + 28) * 2 + 0] = p0 + b_op[0];
                out_final[((size_t)grow * TT + 28) * 2 + 1] = p1 + b_op[1];
            }
        }
    }
    __syncthreads();

    // ================= i = 31 : proj(29) =================
    {
        const unsigned short* h1t = lds + 16384 + (31 & 1) * 8192;
        float p0 = 0.f, p1 = 0.f;
#pragma unroll
        for (int q = 0; q < 2; q++) {
            int col0 = pseg * 16 + q * 8;
            short8 hv = *(const short8*)&h1t[prow * 256 + (col0 ^ psw)];
#pragma unroll
            for (int e = 0; e < 8; e++) {
                float h = bf2f((unsigned short)hv[e]);
                p0 += h * wopl[col0 + e];
                p1 += h * wopl[256 + col0 + e];
            }
        }
#pragma unroll
        for (int sfl = 1; sfl < 16; sfl <<= 1) {
            p0 += __shfl_xor(p0, sfl, 64);
            p1 += __shfl_xor(p1, sfl, 64);
        }
        if (pseg == 0) {
            int grow = blk * 32 + prow;
            out_final[((size_t)grow * TT + 29) * 2 + 0] = p0 + b_op[0];
            out_final[((size_t)grow * TT + 29) * 2 + 1] = p1 + b_op[1];
        }
    }
}

// ---------------- host ----------------
extern "C" void kernel_launch(void* const* d_in, const int* in_sizes, int n_in,
                              void* d_out, int out_size, void* d_ws, size_t ws_size,
                              hipStream_t stream)
{
    const float* obs    = (const float*)d_in[0];
    const float* lane   = (const float*)d_in[1];
    const float* ds     = (const float*)d_in[3];
    const float* W_hid  = (const float*)d_in[4];
    const float* b_hid  = (const float*)d_in[5];
    const float* W_ep   = (const float*)d_in[6];
    const float* b_ep   = (const float*)d_in[7];
    const float* W_conf = (const float*)d_in[8];
    const float* b_conf = (const float*)d_in[9];
    const float* W_ih0  = (const float*)d_in[10];
    const float* W_hh0  = (const float*)d_in[11];
    const float* b_ih0  = (const float*)d_in[12];
    const float* b_hh0  = (const float*)d_in[13];
    const float* W_ih1  = (const float*)d_in[14];
    const float* W_hh1  = (const float*)d_in[15];
    const float* b_ih1  = (const float*)d_in[16];
    const float* b_hh1  = (const float*)d_in[17];
    const float* W_op   = (const float*)d_in[18];
    const float* b_op   = (const float*)d_in[19];

    float* out_final = (float*)d_out;           // [6144*30*2]
    float* out_conf  = out_final + 368640;      // [6144]
    float* out_ep    = out_conf + 6144;         // [6144*2]

    char* ws = (char*)d_ws;
    size_t off = 0;
    auto alloc = [&](size_t bytes) -> void* {
        void* p = ws + off;
        off += (bytes + 255) & ~(size_t)255;
        return p;
    };
    unsigned short* Whid_b = (unsigned short*)alloc(65536 * 2);
    unsigned short* Wih0_b = (unsigned short*)alloc(262144 * 2);
    unsigned short* Wp0    = (unsigned short*)alloc(262144 * 2);
    unsigned short* Wp1    = (unsigned short*)alloc(524288 * 2);
    float*          biasC  = (float*)alloc(1024 * 4);
    unsigned short* Wcomb  = (unsigned short*)alloc((size_t)786432 * 2);
    unsigned short* comb_b = (unsigned short*)alloc(1572864 * 2);
    unsigned short* hid_b  = (unsigned short*)alloc(1572864 * 2);
    float* ep_buf = (float*)alloc(12288 * 4);
    u16x4* gxs4   = (u16x4*)alloc((size_t)1572864 * 8);

    cvt_weights<<<4356, 256, 0, stream>>>(W_hid, W_ih0, W_hh0, W_ih1, W_hh1,
                                          b_ih1, b_hh1,
                                          Whid_b, Wih0_b, Wp0, Wp1, biasC);
    pack_comb<<<3072, 256, 0, stream>>>(Wp0, Wp1, Wcomb);
    build_combined<<<6144, 256, 0, stream>>>(obs, lane, ds, comb_b);
    gemm_hidden<<<96, 256, 0, stream>>>(comb_b, Whid_b, b_hid, hid_b);
    head_kernel<<<24, 256, 0, stream>>>(hid_b, W_ep, b_ep, W_conf, b_conf,
                                        out_conf, out_ep, ep_buf);
    dim3 g2(96, 4);
    gemm_gx0<<<g2, 256, 0, stream>>>(hid_b, Wih0_b, W_ih0, b_ih0, b_hh0, ep_buf, gxs4);

    lstm_persistent<<<192, 512, 0, stream>>>(Wp0, Wp1, Wcomb, gxs4, biasC,
                                             W_op, b_op, out_final);
}

// Round 16
// 1420.534 us; speedup vs baseline: 1.0579x; 1.0579x over previous
//
#include <hip/hip_runtime.h>

// ---------------- types & helpers ----------------
typedef short short8 __attribute__((ext_vector_type(8)));
typedef float f32x4 __attribute__((ext_vector_type(4)));
typedef unsigned short u16x4 __attribute__((ext_vector_type(4)));

#define MFMA_BF16(a, b, c) __builtin_amdgcn_mfma_f32_16x16x32_bf16((a), (b), (c), 0, 0, 0)
#define PIN_AGPR(x) asm volatile("" : "+a"(x))

// async global->LDS, 16B per lane (vmcnt-tracked, NO VGPR destination).
__device__ __forceinline__ void gload_lds16(const void* g, void* l) {
    __builtin_amdgcn_global_load_lds(
        (const __attribute__((address_space(1))) unsigned int*)g,
        (__attribute__((address_space(3))) unsigned int*)l, 16, 0, 0);
}

__device__ __forceinline__ float bf2f(unsigned short u) {
    return __uint_as_float(((unsigned)u) << 16);
}
__device__ __forceinline__ unsigned short f2bf(float f) {
    unsigned u = __float_as_uint(f);
    u += 0x7FFFu + ((u >> 16) & 1u);  // round-to-nearest-even
    return (unsigned short)(u >> 16);
}
// rcp-based (v_rcp_f32, ~1ulp): r14->r15 showed this cuts VALU busy-time ~40%
// (362->222us) with absmax unchanged. (r15's deeper ring was the regression.)
__device__ __forceinline__ float sigm(float x) {
    return __builtin_amdgcn_rcpf(1.0f + __expf(-x));
}
__device__ __forceinline__ float tanh_(float x) {
    float e = __expf(-2.0f * fabsf(x));
    float t = (1.0f - e) * __builtin_amdgcn_rcpf(1.0f + e);
    return copysignf(t, x);
}

#define TT 30

// ---------------- weight conversion / packing ----------------
// Regions: Whid_b 65536 | Wih0_b 262144 | Wp0 262144 (frag-packed W_hh0) |
//   Wp1 524288 (frag-packed [W_ih1|W_hh1]) | biasC 1024
__global__ __launch_bounds__(256) void cvt_weights(
    const float* __restrict__ W_hid, const float* __restrict__ W_ih0,
    const float* __restrict__ W_hh0, const float* __restrict__ W_ih1,
    const float* __restrict__ W_hh1, const float* __restrict__ b_ih1,
    const float* __restrict__ b_hh1,
    unsigned short* __restrict__ Whid_b, unsigned short* __restrict__ Wih0_b,
    unsigned short* __restrict__ Wp0, unsigned short* __restrict__ Wp1,
    float* __restrict__ biasC)
{
    int idx = blockIdx.x * 256 + threadIdx.x;
    if (idx < 65536) { Whid_b[idx] = f2bf(W_hid[idx]); return; }
    idx -= 65536;
    if (idx < 262144) {
        int gc = idx >> 8, k = idx & 255;
        Wih0_b[idx] = f2bf(W_ih0[gc * 258 + k]);
        return;
    }
    idx -= 262144;
    if (idx < 262144) {
        int p = idx;
        int e = p & 7, L = (p >> 3) & 63, kbi = (p >> 9) & 7, n = p >> 12;
        int h16 = n >> 2, g = n & 3;
        int j = g * 256 + h16 * 16 + (L & 15);
        int k = kbi * 32 + (L >> 4) * 8 + e;
        Wp0[p] = f2bf(W_hh0[j * 256 + k]);
        return;
    }
    idx -= 262144;
    if (idx < 524288) {
        int p = idx;
        int e = p & 7, L = (p >> 3) & 63, kbi = (p >> 9) & 15, n = p >> 13;
        int h16 = n >> 2, g = n & 3;
        int j = g * 256 + h16 * 16 + (L & 15);
        int k = kbi * 32 + (L >> 4) * 8 + e;
        float v = (k < 256) ? W_ih1[j * 256 + k] : W_hh1[j * 256 + (k - 256)];
        Wp1[p] = f2bf(v);
        return;
    }
    idx -= 524288;
    if (idx < 1024) biasC[idx] = b_ih1[idx] + b_hh1[idx];
}

// ---------------- pack the per-wave SEQUENTIAL stream Wcomb ----------------
// Wcomb[w][s][g2][L][e]: sub-chunk s (0..95) = 2 gate-slices of 512 ushorts.
//  s<32  (phase A): half=s>>4, kbi=(s>>1)&7, gp=s&1, n=half*4+gp*2+g2 -> Wp0
//  s>=32 (phase B): t=s-32: half=t>>5, kk=(t>>1)&15, gp=t&1           -> Wp1
__global__ __launch_bounds__(256) void pack_comb(
    const unsigned short* __restrict__ Wp0, const unsigned short* __restrict__ Wp1,
    unsigned short* __restrict__ Wcomb)
{
    int idx = blockIdx.x * 256 + threadIdx.x;   // < 786432
    int w = idx / 98304;
    int r = idx - w * 98304;
    int s = r >> 10;
    int q = r & 1023;
    int g2 = q >> 9;
    int le = q & 511;
    unsigned short v;
    if (s < 32) {
        int half = s >> 4, kbi = (s >> 1) & 7, gp = s & 1;
        int nl = half * 4 + gp * 2 + g2;
        v = Wp0[(size_t)(w * 8 + nl) * 4096 + kbi * 512 + le];
    } else {
        int t = s - 32;
        int half = t >> 5, kk = (t >> 1) & 15, gp = t & 1;
        int nl = half * 4 + gp * 2 + g2;
        v = Wp1[(size_t)(w * 8 + nl) * 8192 + kk * 512 + le];
    }
    Wcomb[idx] = v;
}

// combined[n, c] : c<128 obs[b], c<192 lane[b], else ds[kk]
__global__ __launch_bounds__(256) void build_combined(
    const float* __restrict__ obs, const float* __restrict__ lane,
    const float* __restrict__ ds, unsigned short* __restrict__ comb)
{
    int idx = blockIdx.x * 256 + threadIdx.x;  // < 6144*256
    int n = idx >> 8, c = idx & 255;
    int b = n / 6, kk = n - b * 6;
    float v;
    if (c < 128)      v = obs[b * 128 + c];
    else if (c < 192) v = lane[b * 64 + (c - 128)];
    else              v = ds[kk * 64 + (c - 192)];
    comb[idx] = f2bf(v);
}

// ---------------- GEMM: hidden = leakyrelu(combined @ W_hid^T + b_hid) ----------------
__global__ __launch_bounds__(256) void gemm_hidden(
    const unsigned short* __restrict__ A, const unsigned short* __restrict__ B,
    const float* __restrict__ b_hid, unsigned short* __restrict__ hidden)
{
    int wid = threadIdx.x >> 6, lane = threadIdx.x & 63;
    int lrow = lane & 15, kg = lane >> 4;
    int r0 = blockIdx.x * 64;
    int c0 = wid * 64;
    f32x4 acc[4][4];
#pragma unroll
    for (int i = 0; i < 4; i++)
#pragma unroll
        for (int j = 0; j < 4; j++) acc[i][j] = f32x4{0.f, 0.f, 0.f, 0.f};

#pragma unroll
    for (int kb = 0; kb < 256; kb += 32) {
        int k = kb + kg * 8;
        short8 a[4], b[4];
#pragma unroll
        for (int mi = 0; mi < 4; mi++)
            a[mi] = *(const short8*)(A + (size_t)(r0 + mi * 16 + lrow) * 256 + k);
#pragma unroll
        for (int ni = 0; ni < 4; ni++)
            b[ni] = *(const short8*)(B + (size_t)(c0 + ni * 16 + lrow) * 256 + k);
#pragma unroll
        for (int mi = 0; mi < 4; mi++)
#pragma unroll
            for (int ni = 0; ni < 4; ni++)
                acc[mi][ni] = MFMA_BF16(a[mi], b[ni], acc[mi][ni]);
    }
#pragma unroll
    for (int mi = 0; mi < 4; mi++) {
#pragma unroll
        for (int ni = 0; ni < 4; ni++) {
            int col = c0 + ni * 16 + lrow;
            float bb = b_hid[col];
#pragma unroll
            for (int r = 0; r < 4; r++) {
                int row = r0 + mi * 16 + kg * 4 + r;
                float x = acc[mi][ni][r] + bb;
                x = x >= 0.f ? x : 0.1f * x;
                hidden[(size_t)row * 256 + col] = f2bf(x);
            }
        }
    }
}

// ---------------- endpoint / conf head (thread per row) ----------------
__global__ __launch_bounds__(256) void head_kernel(
    const unsigned short* __restrict__ hidden, const float* __restrict__ W_ep,
    const float* __restrict__ b_ep, const float* __restrict__ W_conf,
    const float* __restrict__ b_conf, float* __restrict__ out_conf,
    float* __restrict__ out_ep, float* __restrict__ ep_buf)
{
    int n = blockIdx.x * 256 + threadIdx.x;  // < 6144
    const unsigned short* hr = hidden + (size_t)n * 256;
    float e0 = 0.f, e1 = 0.f, cf = 0.f;
    for (int k = 0; k < 256; k += 8) {
        short8 hv = *(const short8*)(hr + k);
#pragma unroll
        for (int i = 0; i < 8; i++) {
            float h = bf2f((unsigned short)hv[i]);
            e0 += h * W_ep[k + i];
            e1 += h * W_ep[256 + k + i];
            cf += h * W_conf[k + i];
        }
    }
    e0 += b_ep[0]; e1 += b_ep[1]; cf += b_conf[0];
    out_conf[n] = cf;
    out_ep[2 * n] = e0; out_ep[2 * n + 1] = e1;
    ep_buf[2 * n] = e0; ep_buf[2 * n + 1] = e1;
}

// ---------------- GEMM: gx0 (b_ih0+b_hh0 folded, ep rank-2), bf16 frag-layout out ----
__global__ __launch_bounds__(256) void gemm_gx0(
    const unsigned short* __restrict__ A, const unsigned short* __restrict__ B,
    const float* __restrict__ W_ih0f, const float* __restrict__ b_ih0,
    const float* __restrict__ b_hh0, const float* __restrict__ ep_buf,
    u16x4* __restrict__ gxs4)
{
    int wid = threadIdx.x >> 6, lane = threadIdx.x & 63;
    int lrow = lane & 15, kg = lane >> 4;
    int r0 = blockIdx.x * 64;
    int g  = blockIdx.y;                   // gate
    int c0 = g * 256 + wid * 64;
    f32x4 acc[4][4];
#pragma unroll
    for (int i = 0; i < 4; i++)
#pragma unroll
        for (int j = 0; j < 4; j++) acc[i][j] = f32x4{0.f, 0.f, 0.f, 0.f};

#pragma unroll
    for (int kb = 0; kb < 256; kb += 32) {
        int k = kb + kg * 8;
        short8 a[4], b[4];
#pragma unroll
        for (int mi = 0; mi < 4; mi++)
            a[mi] = *(const short8*)(A + (size_t)(r0 + mi * 16 + lrow) * 256 + k);
#pragma unroll
        for (int ni = 0; ni < 4; ni++)
            b[ni] = *(const short8*)(B + (size_t)(c0 + ni * 16 + lrow) * 256 + k);
#pragma unroll
        for (int mi = 0; mi < 4; mi++)
#pragma unroll
            for (int ni = 0; ni < 4; ni++)
                acc[mi][ni] = MFMA_BF16(a[mi], b[ni], acc[mi][ni]);
    }
#pragma unroll
    for (int mi = 0; mi < 4; mi++) {
#pragma unroll
        for (int ni = 0; ni < 4; ni++) {
            int gc = c0 + ni * 16 + lrow;
            float w256 = W_ih0f[(size_t)gc * 258 + 256];
            float w257 = W_ih0f[(size_t)gc * 258 + 257];
            float bb = b_ih0[gc] + b_hh0[gc];
            int h16 = wid * 4 + ni;
            int wv = h16 >> 1, ni2 = h16 & 1;
            int pb = blockIdx.x * 2 + (mi >> 1);
            int idx16 = ((mi & 1) * 2 + ni2) * 4 + g;
            u16x4 pv;
#pragma unroll
            for (int r = 0; r < 4; r++) {
                int row = r0 + mi * 16 + kg * 4 + r;
                float v = acc[mi][ni][r] + bb + ep_buf[2 * row] * w256 + ep_buf[2 * row + 1] * w257;
                pv[r] = f2bf(v);
            }
            gxs4[(size_t)((pb * 8 + wv) * 16 + idx16) * 64 + lane] = pv;
        }
    }
}

// ---------------- persistent 30-step LSTM: counted-vmcnt weight stream --------
// 192 blocks x 512 threads (8 waves). Block owns 32 rows. Wave w: hcols [w*32,+32).
// r14 structure EXACTLY (best: 918us) + rcp-based sigm/tanh only.
// Weights stream global->LDS as ONE sequential 96x2KB-chunk stream per iter
// (Wcomb), 4-buffer ring, 3 chunks ahead, s_waitcnt vmcnt(4) per chunk (T4).
// In-flight weights use ZERO VGPRs -> minimal spill.
// LDS 130KB: h0 pp @0/16KB, h1 pp @32/48KB (XOR swizzle col^((row&7)<<3)),
// ring bufs @64KB+w*8KB, W_op copy @128KB. gx in 16 regs; c AGPR-pinned;
// biasL1 in 8 regs; NO other vmem in hot loop (counted waits stay valid).
#define STG(sv)                                                              \
    {                                                                        \
        const unsigned short* _s = wc + (size_t)(sv) * 1024;                 \
        unsigned short* _d = wbuf_base + ((sv) & 3) * 1024;                  \
        gload_lds16(_s, _d);                                                 \
        gload_lds16(_s + 512, _d + 512);                                     \
    }

#define EPIA(HALF)                                                           \
    {                                                                        \
        int col = w * 32 + (HALF) * 16 + lrow;                               \
        _Pragma("unroll") for (int mi = 0; mi < 2; mi++) {                   \
            u16x4 gI = gxr[(mi * 2 + (HALF)) * 4 + 0];                       \
            u16x4 gF = gxr[(mi * 2 + (HALF)) * 4 + 1];                       \
            u16x4 gG = gxr[(mi * 2 + (HALF)) * 4 + 2];                       \
            u16x4 gO = gxr[(mi * 2 + (HALF)) * 4 + 3];                       \
            f32x4 cp = c0r[mi][(HALF)];                                      \
            f32x4 cnv;                                                       \
            _Pragma("unroll") for (int r = 0; r < 4; r++) {                  \
                float gi = acc[mi][0][r] + bf2f(gI[r]);                      \
                float gf = acc[mi][1][r] + bf2f(gF[r]);                      \
                float gg = acc[mi][2][r] + bf2f(gG[r]);                      \
                float go = acc[mi][3][r] + bf2f(gO[r]);                      \
                float cn = sigm(gf) * cp[r] + sigm(gi) * tanh_(gg);          \
                float hn = sigm(go) * tanh_(cn);                             \
                cnv[r] = cn;                                                 \
                int row = mi * 16 + kg * 4 + r;                              \
                h0new[row * 256 + (col ^ ((row & 7) << 3))] = f2bf(hn);      \
            }                                                                \
            c0r[mi][(HALF)] = cnv;                                           \
            PIN_AGPR(c0r[mi][(HALF)]);                                       \
            _Pragma("unroll") for (int g = 0; g < 4; g++)                    \
                acc[mi][g] = f32x4{0.f, 0.f, 0.f, 0.f};                      \
        }                                                                    \
    }

#define EPIB(HALF)                                                           \
    {                                                                        \
        int col = w * 32 + (HALF) * 16 + lrow;                               \
        _Pragma("unroll") for (int mi = 0; mi < 2; mi++) {                   \
            f32x4 cp = c1r[mi][(HALF)];                                      \
            f32x4 cnv;                                                       \
            _Pragma("unroll") for (int r = 0; r < 4; r++) {                  \
                float gi = acc[mi][0][r] + biasL1[(HALF) * 4 + 0];           \
                float gf = acc[mi][1][r] + biasL1[(HALF) * 4 + 1];           \
                float gg = acc[mi][2][r] + biasL1[(HALF) * 4 + 2];           \
                float go = acc[mi][3][r] + biasL1[(HALF) * 4 + 3];           \
                float cn = sigm(gf) * cp[r] + sigm(gi) * tanh_(gg);          \
                float hn = sigm(go) * tanh_(cn);                             \
                cnv[r] = cn;                                                 \
                int row = mi * 16 + kg * 4 + r;                              \
                h1new[row * 256 + (col ^ ((row & 7) << 3))] = f2bf(hn);      \
            }                                                                \
            c1r[mi][(HALF)] = cnv;                                           \
            PIN_AGPR(c1r[mi][(HALF)]);                                       \
            _Pragma("unroll") for (int g = 0; g < 4; g++)                    \
                acc[mi][g] = f32x4{0.f, 0.f, 0.f, 0.f};                      \
        }                                                                    \
    }

__global__ __launch_bounds__(512, 1) void lstm_persistent(
    const unsigned short* __restrict__ Wp0, const unsigned short* __restrict__ Wp1,
    const unsigned short* __restrict__ Wcomb,
    const u16x4* __restrict__ gxs4, const float* __restrict__ biasC,
    const float* __restrict__ W_op, const float* __restrict__ b_op,
    float* __restrict__ out_final)
{
    __shared__ unsigned short lds[66560];   // 130 KB

    const int blk  = blockIdx.x;            // rows blk*32 .. +32
    const int w    = threadIdx.x >> 6;
    const int lane = threadIdx.x & 63;
    const int lrow = lane & 15;
    const int kg   = lane >> 4;
    const int sw   = (lrow & 7) << 3;       // A-frag k-swizzle

    // W_op copy into LDS (keeps proj off vmcnt in the hot loop)
    float* wopl = (float*)&lds[65536];
    wopl[threadIdx.x] = W_op[threadIdx.x];

    // gx preload into registers — 16 VGPR
    u16x4 gxr[16];
    {
        const u16x4* gxw = gxs4 + (size_t)(blk * 8 + w) * 16 * 64;
#pragma unroll
        for (int j = 0; j < 16; j++) gxr[j] = gxw[j * 64 + lane];
    }
    // L1 biases in 8 regs (keeps them off vmcnt in the hot loop)
    float biasL1[8];
#pragma unroll
    for (int ni2 = 0; ni2 < 2; ni2++)
#pragma unroll
        for (int g = 0; g < 4; g++)
            biasL1[ni2 * 4 + g] = biasC[g * 256 + w * 32 + ni2 * 16 + lrow];

    f32x4 c0r[2][2], c1r[2][2];
#pragma unroll
    for (int mi = 0; mi < 2; mi++)
#pragma unroll
        for (int ni2 = 0; ni2 < 2; ni2++) {
            c0r[mi][ni2] = f32x4{0.f, 0.f, 0.f, 0.f};
            c1r[mi][ni2] = f32x4{0.f, 0.f, 0.f, 0.f};
            PIN_AGPR(c0r[mi][ni2]);
            PIN_AGPR(c1r[mi][ni2]);
        }

    const unsigned short* wc = Wcomb + (size_t)w * 98304 + (size_t)lane * 8;
    unsigned short* wbuf_base = &lds[32768 + w * 4096];        // wave-uniform dest
    const unsigned short* wbufL = wbuf_base + lane * 8;        // per-lane read
    const unsigned short* wp0w = Wp0 + (size_t)w * 32768 + (size_t)lane * 8;
    const unsigned short* wp1w = Wp1 + (size_t)w * 65536 + (size_t)lane * 8;

    const int prow = threadIdx.x >> 4;
    const int pseg = threadIdx.x & 15;
    const int psw  = (prow & 7) << 3;

    f32x4 acc[2][4];
#pragma unroll
    for (int mi = 0; mi < 2; mi++)
#pragma unroll
        for (int g = 0; g < 4; g++) acc[mi][g] = f32x4{0.f, 0.f, 0.f, 0.f};

    // ================= i = 0 : h0[0] from gx only =================
    {
        unsigned short* h0new = lds;  // buffer 0
        EPIA(0);
        EPIA(1);
    }
    __syncthreads();

    // ================= i = 1 : direct A + direct B-init =================
    {
        unsigned short* h0new = lds + 8192;       // h0[1]
        const unsigned short* h0prev = lds;       // h0[0]
#pragma unroll
        for (int half = 0; half < 2; half++) {
#pragma unroll
            for (int kbi = 0; kbi < 8; kbi++) {
                short8 a0, a1, b[4];
                int k = (kbi * 32 + kg * 8) ^ sw;
                a0 = *(const short8*)&h0prev[lrow * 256 + k];
                a1 = *(const short8*)&h0prev[(16 + lrow) * 256 + k];
#pragma unroll
                for (int g = 0; g < 4; g++)
                    b[g] = *(const short8*)&wp0w[(size_t)(((half * 4 + g) * 8 + kbi) * 512)];
#pragma unroll
                for (int g = 0; g < 4; g++) {
                    acc[0][g] = MFMA_BF16(a0, b[g], acc[0][g]);
                    acc[1][g] = MFMA_BF16(a1, b[g], acc[1][g]);
                }
            }
            if (half == 0) { EPIA(0); } else { EPIA(1); }
        }
        // B-init: h1[0], c1 = i-gate * g-gate only
        unsigned short* h1new = lds + 16384;      // h1[0] -> ping 0
#pragma unroll
        for (int half = 0; half < 2; half++) {
#pragma unroll
            for (int kbi = 0; kbi < 8; kbi++) {
                short8 a0, a1, b[4];
                int k = (kbi * 32 + kg * 8) ^ sw;
                a0 = *(const short8*)&h0prev[lrow * 256 + k];
                a1 = *(const short8*)&h0prev[(16 + lrow) * 256 + k];
#pragma unroll
                for (int g = 0; g < 4; g++)
                    b[g] = *(const short8*)&wp1w[(size_t)(((half * 4 + g) * 16 + kbi) * 512)];
#pragma unroll
                for (int g = 0; g < 4; g++) {
                    acc[0][g] = MFMA_BF16(a0, b[g], acc[0][g]);
                    acc[1][g] = MFMA_BF16(a1, b[g], acc[1][g]);
                }
            }
            int col = w * 32 + half * 16 + lrow;
#pragma unroll
            for (int mi = 0; mi < 2; mi++) {
                f32x4 cnv;
#pragma unroll
                for (int r = 0; r < 4; r++) {
                    float gi = acc[mi][0][r] + biasL1[half * 4 + 0];
                    float gg = acc[mi][2][r] + biasL1[half * 4 + 2];
                    float go = acc[mi][3][r] + biasL1[half * 4 + 3];
                    float cn = sigm(gi) * tanh_(gg);
                    float hn = sigm(go) * tanh_(cn);
                    cnv[r] = cn;
                    int row = mi * 16 + kg * 4 + r;
                    h1new[row * 256 + (col ^ ((row & 7) << 3))] = f2bf(hn);
                }
                c1r[mi][half] = cnv;
                PIN_AGPR(c1r[mi][half]);
#pragma unroll
                for (int g = 0; g < 4; g++) acc[mi][g] = f32x4{0.f, 0.f, 0.f, 0.f};
            }
        }
    }
    __syncthreads();

    // ================= i = 2..29 : streamed full iterations =================
    for (int i = 2; i <= 29; ++i) {
        unsigned short* h0new = lds + (i & 1) * 8192;
        const unsigned short* h0prev = lds + ((i - 1) & 1) * 8192;
        const unsigned short* h1prev = lds + 16384 + (i & 1) * 8192;
        unsigned short* h1new = lds + 16384 + ((i - 1) & 1) * 8192;

        STG(0); STG(1); STG(2);

        short8 a0, a1;
        // ---- phase A: chunks 0..31 ----
#pragma unroll
        for (int s = 0; s < 32; s++) {
            const int kbi = (s >> 1) & 7;
            const int g0 = (s & 1) * 2;
            if ((s & 1) == 0) {
                int k = (kbi * 32 + kg * 8) ^ sw;
                a0 = *(const short8*)&h0prev[lrow * 256 + k];
                a1 = *(const short8*)&h0prev[(16 + lrow) * 256 + k];
            }
            asm volatile("s_waitcnt vmcnt(4)" ::: "memory");
            short8 b0 = *(const short8*)(wbufL + (s & 3) * 1024);
            short8 b1 = *(const short8*)(wbufL + (s & 3) * 1024 + 512);
            acc[0][g0]     = MFMA_BF16(a0, b0, acc[0][g0]);
            acc[1][g0]     = MFMA_BF16(a1, b0, acc[1][g0]);
            acc[0][g0 + 1] = MFMA_BF16(a0, b1, acc[0][g0 + 1]);
            acc[1][g0 + 1] = MFMA_BF16(a1, b1, acc[1][g0 + 1]);
            STG(s + 3);
            if (s == 15) { EPIA(0); }
        }
        EPIA(1);

        // ---- phase B: chunks 32..95 ----
#pragma unroll
        for (int s = 32; s < 96; s++) {
            const int t = s - 32;
            const int kk = (t >> 1) & 15;
            const int g0 = (t & 1) * 2;
            if ((t & 1) == 0) {
                const unsigned short* hsrc = (kk < 8) ? h0prev : h1prev;
                int k = ((kk & 7) * 32 + kg * 8) ^ sw;
                a0 = *(const short8*)&hsrc[lrow * 256 + k];
                a1 = *(const short8*)&hsrc[(16 + lrow) * 256 + k];
            }
            if (s <= 93)      asm volatile("s_waitcnt vmcnt(4)" ::: "memory");
            else if (s == 94) asm volatile("s_waitcnt vmcnt(2)" ::: "memory");
            else              asm volatile("s_waitcnt vmcnt(0)" ::: "memory");
            short8 b0 = *(const short8*)(wbufL + (s & 3) * 1024);
            short8 b1 = *(const short8*)(wbufL + (s & 3) * 1024 + 512);
            acc[0][g0]     = MFMA_BF16(a0, b0, acc[0][g0]);
            acc[1][g0]     = MFMA_BF16(a1, b0, acc[1][g0]);
            acc[0][g0 + 1] = MFMA_BF16(a0, b1, acc[0][g0 + 1]);
            acc[1][g0 + 1] = MFMA_BF16(a1, b1, acc[1][g0 + 1]);
            if (s + 3 < 96) STG(s + 3);
            if (t == 31) { EPIB(0); }
        }
        EPIB(1);

        // ---- out-projection: t = i-2 (reads h1[i-2]) ----
        {
            const unsigned short* h1t = lds + 16384 + (i & 1) * 8192;
            float p0 = 0.f, p1 = 0.f;
#pragma unroll
            for (int q = 0; q < 2; q++) {
                int col0 = pseg * 16 + q * 8;
                short8 hv = *(const short8*)&h1t[prow * 256 + (col0 ^ psw)];
#pragma unroll
                for (int e = 0; e < 8; e++) {
                    float h = bf2f((unsigned short)hv[e]);
                    p0 += h * wopl[col0 + e];
                    p1 += h * wopl[256 + col0 + e];
                }
            }
#pragma unroll
            for (int sfl = 1; sfl < 16; sfl <<= 1) {
                p0 += __shfl_xor(p0, sfl, 64);
                p1 += __shfl_xor(p1, sfl, 64);
            }
            if (pseg == 0) {
                int grow = blk * 32 + prow;
                int t = i - 2;
                out_final[((size_t)grow * TT + t) * 2 + 0] = p0 + b_op[0];
                out_final[((size_t)grow * TT + t) * 2 + 1] = p1 + b_op[1];
            }
        }
        __syncthreads();
    }

    // ================= i = 30 : direct B + proj(28) =================
    {
        const int i = 30;
        const unsigned short* h0prev = lds + ((i - 1) & 1) * 8192;
        const unsigned short* h1prev = lds + 16384 + (i & 1) * 8192;
        unsigned short* h1new = lds + 16384 + ((i - 1) & 1) * 8192;
#pragma unroll
        for (int half = 0; half < 2; half++) {
#pragma unroll
            for (int kk = 0; kk < 16; kk++) {
                short8 a0, a1, b[4];
                const unsigned short* hsrc = (kk < 8) ? h0prev : h1prev;
                int k = ((kk & 7) * 32 + kg * 8) ^ sw;
                a0 = *(const short8*)&hsrc[lrow * 256 + k];
                a1 = *(const short8*)&hsrc[(16 + lrow) * 256 + k];
#pragma unroll
                for (int g = 0; g < 4; g++)
                    b[g] = *(const short8*)&wp1w[(size_t)(((half * 4 + g) * 16 + kk) * 512)];
#pragma unroll
                for (int g = 0; g < 4; g++) {
                    acc[0][g] = MFMA_BF16(a0, b[g], acc[0][g]);
                    acc[1][g] = MFMA_BF16(a1, b[g], acc[1][g]);
                }
            }
            if (half == 0) { EPIB(0); } else { EPIB(1); }
        }
        {
            const unsigned short* h1t = lds + 16384 + (i & 1) * 8192;
            float p0 = 0.f, p1 = 0.f;
#pragma unroll
            for (int q = 0; q < 2; q++) {
                int col0 = pseg * 16 + q * 8;
                short8 hv = *(const short8*)&h1t[prow * 256 + (col0 ^ psw)];
#pragma unroll
                for (int e = 0; e < 8; e++) {
                    float h = bf2f((unsigned short)hv[e]);
                    p0 += h * wopl[col0 + e];
                    p1 += h * wopl[256 + col0 + e];
                }
            }
#pragma unroll
            for (int sfl = 1; sfl < 16; sfl <<= 1) {
                p0 += __shfl_xor(p0, sfl, 64);
                p1 += __shfl_xor(p1, sfl, 64);
            }
            if (pseg == 0) {
                int grow = blk * 32 + prow;
                out_final[((size_t)grow * TT + 28) * 2 + 0] = p0 + b_op[0];
                out_final[((size_t)grow * TT + 28) * 2 + 1] = p1 + b_op[1];
            }
        }
    }
    __syncthreads();

    // ================= i = 31 : proj(29) =================
    {
        const unsigned short* h1t = lds + 16384 + (31 & 1) * 8192;
        float p0 = 0.f, p1 = 0.f;
#pragma unroll
        for (int q = 0; q < 2; q++) {
            int col0 = pseg * 16 + q * 8;
            short8 hv = *(const short8*)&h1t[prow * 256 + (col0 ^ psw)];
#pragma unroll
            for (int e = 0; e < 8; e++) {
                float h = bf2f((unsigned short)hv[e]);
                p0 += h * wopl[col0 + e];
                p1 += h * wopl[256 + col0 + e];
            }
        }
#pragma unroll
        for (int sfl = 1; sfl < 16; sfl <<= 1) {
            p0 += __shfl_xor(p0, sfl, 64);
            p1 += __shfl_xor(p1, sfl, 64);
        }
        if (pseg == 0) {
            int grow = blk * 32 + prow;
            out_final[((size_t)grow * TT + 29) * 2 + 0] = p0 + b_op[0];
            out_final[((size_t)grow * TT + 29) * 2 + 1] = p1 + b_op[1];
        }
    }
}

// ---------------- host ----------------
extern "C" void kernel_launch(void* const* d_in, const int* in_sizes, int n_in,
                              void* d_out, int out_size, void* d_ws, size_t ws_size,
                              hipStream_t stream)
{
    const float* obs    = (const float*)d_in[0];
    const float* lane   = (const float*)d_in[1];
    const float* ds     = (const float*)d_in[3];
    const float* W_hid  = (const float*)d_in[4];
    const float* b_hid  = (const float*)d_in[5];
    const float* W_ep   = (const float*)d_in[6];
    const float* b_ep   = (const float*)d_in[7];
    const float* W_conf = (const float*)d_in[8];
    const float* b_conf = (const float*)d_in[9];
    const float* W_ih0  = (const float*)d_in[10];
    const float* W_hh0  = (const float*)d_in[11];
    const float* b_ih0  = (const float*)d_in[12];
    const float* b_hh0  = (const float*)d_in[13];
    const float* W_ih1  = (const float*)d_in[14];
    const float* W_hh1  = (const float*)d_in[15];
    const float* b_ih1  = (const float*)d_in[16];
    const float* b_hh1  = (const float*)d_in[17];
    const float* W_op   = (const float*)d_in[18];
    const float* b_op   = (const float*)d_in[19];

    float* out_final = (float*)d_out;           // [6144*30*2]
    float* out_conf  = out_final + 368640;      // [6144]
    float* out_ep    = out_conf + 6144;         // [6144*2]

    char* ws = (char*)d_ws;
    size_t off = 0;
    auto alloc = [&](size_t bytes) -> void* {
        void* p = ws + off;
        off += (bytes + 255) & ~(size_t)255;
        return p;
    };
    unsigned short* Whid_b = (unsigned short*)alloc(65536 * 2);
    unsigned short* Wih0_b = (unsigned short*)alloc(262144 * 2);
    unsigned short* Wp0    = (unsigned short*)alloc(262144 * 2);
    unsigned short* Wp1    = (unsigned short*)alloc(524288 * 2);
    float*          biasC  = (float*)alloc(1024 * 4);
    unsigned short* Wcomb  = (unsigned short*)alloc((size_t)786432 * 2);
    unsigned short* comb_b = (unsigned short*)alloc(1572864 * 2);
    unsigned short* hid_b  = (unsigned short*)alloc(1572864 * 2);
    float* ep_buf = (float*)alloc(12288 * 4);
    u16x4* gxs4   = (u16x4*)alloc((size_t)1572864 * 8);

    cvt_weights<<<4356, 256, 0, stream>>>(W_hid, W_ih0, W_hh0, W_ih1, W_hh1,
                                          b_ih1, b_hh1,
                                          Whid_b, Wih0_b, Wp0, Wp1, biasC);
    pack_comb<<<3072, 256, 0, stream>>>(Wp0, Wp1, Wcomb);
    build_combined<<<6144, 256, 0, stream>>>(obs, lane, ds, comb_b);
    gemm_hidden<<<96, 256, 0, stream>>>(comb_b, Whid_b, b_hid, hid_b);
    head_kernel<<<24, 256, 0, stream>>>(hid_b, W_ep, b_ep, W_conf, b_conf,
                                        out_conf, out_ep, ep_buf);
    dim3 g2(96, 4);
    gemm_gx0<<<g2, 256, 0, stream>>>(hid_b, Wih0_b, W_ih0, b_ih0, b_hh0, ep_buf, gxs4);

    lstm_persistent<<<192, 512, 0, stream>>>(Wp0, Wp1, Wcomb, gxs4, biasC,
                                             W_op, b_op, out_final);
}

// Round 17
// 1401.086 us; speedup vs baseline: 1.0726x; 1.0139x over previous
//
#include <hip/hip_runtime.h>

// ---------------- types & helpers ----------------
typedef short short8 __attribute__((ext_vector_type(8)));
typedef float f32x4 __attribute__((ext_vector_type(4)));
typedef unsigned short u16x4 __attribute__((ext_vector_type(4)));

#define MFMA_BF16(a, b, c) __builtin_amdgcn_mfma_f32_16x16x32_bf16((a), (b), (c), 0, 0, 0)
#define PIN_AGPR(x) asm volatile("" : "+a"(x))

// async global->LDS, 16B per lane (vmcnt-tracked, NO VGPR destination).
__device__ __forceinline__ void gload_lds16(const void* g, void* l) {
    __builtin_amdgcn_global_load_lds(
        (const __attribute__((address_space(1))) unsigned int*)g,
        (__attribute__((address_space(3))) unsigned int*)l, 16, 0, 0);
}

__device__ __forceinline__ float bf2f(unsigned short u) {
    return __uint_as_float(((unsigned)u) << 16);
}
__device__ __forceinline__ unsigned short f2bf(float f) {
    unsigned u = __float_as_uint(f);
    u += 0x7FFFu + ((u >> 16) & 1u);  // round-to-nearest-even
    return (unsigned short)(u >> 16);
}
// rcp-based (v_rcp_f32, ~1ulp): cuts VALU busy-time ~40% vs full divides (r14->r16).
__device__ __forceinline__ float sigm(float x) {
    return __builtin_amdgcn_rcpf(1.0f + __expf(-x));
}
__device__ __forceinline__ float tanh_(float x) {
    float e = __expf(-2.0f * fabsf(x));
    float t = (1.0f - e) * __builtin_amdgcn_rcpf(1.0f + e);
    return copysignf(t, x);
}

#define TT 30

// ---------------- weight conversion / packing ----------------
// Regions: Whid_b 65536 | Wih0_b 262144 | Wp0 262144 (frag-packed W_hh0) |
//   Wp1 524288 (frag-packed [W_ih1|W_hh1]) | biasC 1024
__global__ __launch_bounds__(256) void cvt_weights(
    const float* __restrict__ W_hid, const float* __restrict__ W_ih0,
    const float* __restrict__ W_hh0, const float* __restrict__ W_ih1,
    const float* __restrict__ W_hh1, const float* __restrict__ b_ih1,
    const float* __restrict__ b_hh1,
    unsigned short* __restrict__ Whid_b, unsigned short* __restrict__ Wih0_b,
    unsigned short* __restrict__ Wp0, unsigned short* __restrict__ Wp1,
    float* __restrict__ biasC)
{
    int idx = blockIdx.x * 256 + threadIdx.x;
    if (idx < 65536) { Whid_b[idx] = f2bf(W_hid[idx]); return; }
    idx -= 65536;
    if (idx < 262144) {
        int gc = idx >> 8, k = idx & 255;
        Wih0_b[idx] = f2bf(W_ih0[gc * 258 + k]);
        return;
    }
    idx -= 262144;
    if (idx < 262144) {
        int p = idx;
        int e = p & 7, L = (p >> 3) & 63, kbi = (p >> 9) & 7, n = p >> 12;
        int h16 = n >> 2, g = n & 3;
        int j = g * 256 + h16 * 16 + (L & 15);
        int k = kbi * 32 + (L >> 4) * 8 + e;
        Wp0[p] = f2bf(W_hh0[j * 256 + k]);
        return;
    }
    idx -= 262144;
    if (idx < 524288) {
        int p = idx;
        int e = p & 7, L = (p >> 3) & 63, kbi = (p >> 9) & 15, n = p >> 13;
        int h16 = n >> 2, g = n & 3;
        int j = g * 256 + h16 * 16 + (L & 15);
        int k = kbi * 32 + (L >> 4) * 8 + e;
        float v = (k < 256) ? W_ih1[j * 256 + k] : W_hh1[j * 256 + (k - 256)];
        Wp1[p] = f2bf(v);
        return;
    }
    idx -= 524288;
    if (idx < 1024) biasC[idx] = b_ih1[idx] + b_hh1[idx];
}

// ---------------- pack the per-wave SEQUENTIAL stream Wcomb ----------------
// Wcomb[w][s][g2][L][e]: sub-chunk s (0..95) = 2 gate-slices of 512 ushorts.
//  s<32  (phase A): half=s>>4, kbi=(s>>1)&7, gp=s&1, n=half*4+gp*2+g2 -> Wp0
//  s>=32 (phase B): t=s-32: half=t>>5, kk=(t>>1)&15, gp=t&1           -> Wp1
__global__ __launch_bounds__(256) void pack_comb(
    const unsigned short* __restrict__ Wp0, const unsigned short* __restrict__ Wp1,
    unsigned short* __restrict__ Wcomb)
{
    int idx = blockIdx.x * 256 + threadIdx.x;   // < 786432
    int w = idx / 98304;
    int r = idx - w * 98304;
    int s = r >> 10;
    int q = r & 1023;
    int g2 = q >> 9;
    int le = q & 511;
    unsigned short v;
    if (s < 32) {
        int half = s >> 4, kbi = (s >> 1) & 7, gp = s & 1;
        int nl = half * 4 + gp * 2 + g2;
        v = Wp0[(size_t)(w * 8 + nl) * 4096 + kbi * 512 + le];
    } else {
        int t = s - 32;
        int half = t >> 5, kk = (t >> 1) & 15, gp = t & 1;
        int nl = half * 4 + gp * 2 + g2;
        v = Wp1[(size_t)(w * 8 + nl) * 8192 + kk * 512 + le];
    }
    Wcomb[idx] = v;
}

// combined[n, c] : c<128 obs[b], c<192 lane[b], else ds[kk]
__global__ __launch_bounds__(256) void build_combined(
    const float* __restrict__ obs, const float* __restrict__ lane,
    const float* __restrict__ ds, unsigned short* __restrict__ comb)
{
    int idx = blockIdx.x * 256 + threadIdx.x;  // < 6144*256
    int n = idx >> 8, c = idx & 255;
    int b = n / 6, kk = n - b * 6;
    float v;
    if (c < 128)      v = obs[b * 128 + c];
    else if (c < 192) v = lane[b * 64 + (c - 128)];
    else              v = ds[kk * 64 + (c - 192)];
    comb[idx] = f2bf(v);
}

// ---------------- GEMM: hidden = leakyrelu(combined @ W_hid^T + b_hid) ----------------
__global__ __launch_bounds__(256) void gemm_hidden(
    const unsigned short* __restrict__ A, const unsigned short* __restrict__ B,
    const float* __restrict__ b_hid, unsigned short* __restrict__ hidden)
{
    int wid = threadIdx.x >> 6, lane = threadIdx.x & 63;
    int lrow = lane & 15, kg = lane >> 4;
    int r0 = blockIdx.x * 64;
    int c0 = wid * 64;
    f32x4 acc[4][4];
#pragma unroll
    for (int i = 0; i < 4; i++)
#pragma unroll
        for (int j = 0; j < 4; j++) acc[i][j] = f32x4{0.f, 0.f, 0.f, 0.f};

#pragma unroll
    for (int kb = 0; kb < 256; kb += 32) {
        int k = kb + kg * 8;
        short8 a[4], b[4];
#pragma unroll
        for (int mi = 0; mi < 4; mi++)
            a[mi] = *(const short8*)(A + (size_t)(r0 + mi * 16 + lrow) * 256 + k);
#pragma unroll
        for (int ni = 0; ni < 4; ni++)
            b[ni] = *(const short8*)(B + (size_t)(c0 + ni * 16 + lrow) * 256 + k);
#pragma unroll
        for (int mi = 0; mi < 4; mi++)
#pragma unroll
            for (int ni = 0; ni < 4; ni++)
                acc[mi][ni] = MFMA_BF16(a[mi], b[ni], acc[mi][ni]);
    }
#pragma unroll
    for (int mi = 0; mi < 4; mi++) {
#pragma unroll
        for (int ni = 0; ni < 4; ni++) {
            int col = c0 + ni * 16 + lrow;
            float bb = b_hid[col];
#pragma unroll
            for (int r = 0; r < 4; r++) {
                int row = r0 + mi * 16 + kg * 4 + r;
                float x = acc[mi][ni][r] + bb;
                x = x >= 0.f ? x : 0.1f * x;
                hidden[(size_t)row * 256 + col] = f2bf(x);
            }
        }
    }
}

// ---------------- endpoint / conf head (thread per row) ----------------
__global__ __launch_bounds__(256) void head_kernel(
    const unsigned short* __restrict__ hidden, const float* __restrict__ W_ep,
    const float* __restrict__ b_ep, const float* __restrict__ W_conf,
    const float* __restrict__ b_conf, float* __restrict__ out_conf,
    float* __restrict__ out_ep, float* __restrict__ ep_buf)
{
    int n = blockIdx.x * 256 + threadIdx.x;  // < 6144
    const unsigned short* hr = hidden + (size_t)n * 256;
    float e0 = 0.f, e1 = 0.f, cf = 0.f;
    for (int k = 0; k < 256; k += 8) {
        short8 hv = *(const short8*)(hr + k);
#pragma unroll
        for (int i = 0; i < 8; i++) {
            float h = bf2f((unsigned short)hv[i]);
            e0 += h * W_ep[k + i];
            e1 += h * W_ep[256 + k + i];
            cf += h * W_conf[k + i];
        }
    }
    e0 += b_ep[0]; e1 += b_ep[1]; cf += b_conf[0];
    out_conf[n] = cf;
    out_ep[2 * n] = e0; out_ep[2 * n + 1] = e1;
    ep_buf[2 * n] = e0; ep_buf[2 * n + 1] = e1;
}

// ---------------- GEMM: gx0 (b_ih0+b_hh0 folded, ep rank-2), bf16 frag-layout out ----
__global__ __launch_bounds__(256) void gemm_gx0(
    const unsigned short* __restrict__ A, const unsigned short* __restrict__ B,
    const float* __restrict__ W_ih0f, const float* __restrict__ b_ih0,
    const float* __restrict__ b_hh0, const float* __restrict__ ep_buf,
    u16x4* __restrict__ gxs4)
{
    int wid = threadIdx.x >> 6, lane = threadIdx.x & 63;
    int lrow = lane & 15, kg = lane >> 4;
    int r0 = blockIdx.x * 64;
    int g  = blockIdx.y;                   // gate
    int c0 = g * 256 + wid * 64;
    f32x4 acc[4][4];
#pragma unroll
    for (int i = 0; i < 4; i++)
#pragma unroll
        for (int j = 0; j < 4; j++) acc[i][j] = f32x4{0.f, 0.f, 0.f, 0.f};

#pragma unroll
    for (int kb = 0; kb < 256; kb += 32) {
        int k = kb + kg * 8;
        short8 a[4], b[4];
#pragma unroll
        for (int mi = 0; mi < 4; mi++)
            a[mi] = *(const short8*)(A + (size_t)(r0 + mi * 16 + lrow) * 256 + k);
#pragma unroll
        for (int ni = 0; ni < 4; ni++)
            b[ni] = *(const short8*)(B + (size_t)(c0 + ni * 16 + lrow) * 256 + k);
#pragma unroll
        for (int mi = 0; mi < 4; mi++)
#pragma unroll
            for (int ni = 0; ni < 4; ni++)
                acc[mi][ni] = MFMA_BF16(a[mi], b[ni], acc[mi][ni]);
    }
#pragma unroll
    for (int mi = 0; mi < 4; mi++) {
#pragma unroll
        for (int ni = 0; ni < 4; ni++) {
            int gc = c0 + ni * 16 + lrow;
            float w256 = W_ih0f[(size_t)gc * 258 + 256];
            float w257 = W_ih0f[(size_t)gc * 258 + 257];
            float bb = b_ih0[gc] + b_hh0[gc];
            int h16 = wid * 4 + ni;
            int wv = h16 >> 1, ni2 = h16 & 1;
            int pb = blockIdx.x * 2 + (mi >> 1);
            int idx16 = ((mi & 1) * 2 + ni2) * 4 + g;
            u16x4 pv;
#pragma unroll
            for (int r = 0; r < 4; r++) {
                int row = r0 + mi * 16 + kg * 4 + r;
                float v = acc[mi][ni][r] + bb + ep_buf[2 * row] * w256 + ep_buf[2 * row + 1] * w257;
                pv[r] = f2bf(v);
            }
            gxs4[(size_t)((pb * 8 + wv) * 16 + idx16) * 64 + lane] = pv;
        }
    }
}

// ---------------- persistent 30-step LSTM: counted-vmcnt weight stream --------
// 192 blocks x 512 threads (8 waves). Block owns 32 rows. Wave w: hcols [w*32,+32).
// r14 structure (best memory profile) + rcp sigm/tanh (best VALU profile) +
// gxr[16] (32 VGPR) and biasL1 (8 VGPR) PARKED IN AGPRs between uses: frees
// ~40 arch VGPRs to absorb the rcp-induced regalloc pressure (r16: rcp alone
// grew spill 76->128MB and FETCH 485MB->1.33GB -- the L2 capacity cliff).
// Weights stream global->LDS as ONE sequential 96x2KB-chunk stream per iter
// (Wcomb), 4-buffer ring, 3 chunks ahead, s_waitcnt vmcnt(4) per chunk (T4).
// LDS 130KB: h0 pp @0/16KB, h1 pp @32/48KB (XOR swizzle col^((row&7)<<3)),
// ring bufs @64KB+w*8KB, W_op copy @128KB. c AGPR-pinned. NO other vmem in
// hot loop (counted waits stay valid).
#define STG(sv)                                                              \
    {                                                                        \
        const unsigned short* _s = wc + (size_t)(sv) * 1024;                 \
        unsigned short* _d = wbuf_base + ((sv) & 3) * 1024;                  \
        gload_lds16(_s, _d);                                                 \
        gload_lds16(_s + 512, _d + 512);                                     \
    }

#define EPIA(HALF)                                                           \
    {                                                                        \
        int col = w * 32 + (HALF) * 16 + lrow;                               \
        _Pragma("unroll") for (int mi = 0; mi < 2; mi++) {                   \
            u16x4 gI = gxr[(mi * 2 + (HALF)) * 4 + 0];                       \
            u16x4 gF = gxr[(mi * 2 + (HALF)) * 4 + 1];                       \
            u16x4 gG = gxr[(mi * 2 + (HALF)) * 4 + 2];                       \
            u16x4 gO = gxr[(mi * 2 + (HALF)) * 4 + 3];                       \
            f32x4 cp = c0r[mi][(HALF)];                                      \
            f32x4 cnv;                                                       \
            _Pragma("unroll") for (int r = 0; r < 4; r++) {                  \
                float gi = acc[mi][0][r] + bf2f(gI[r]);                      \
                float gf = acc[mi][1][r] + bf2f(gF[r]);                      \
                float gg = acc[mi][2][r] + bf2f(gG[r]);                      \
                float go = acc[mi][3][r] + bf2f(gO[r]);                      \
                float cn = sigm(gf) * cp[r] + sigm(gi) * tanh_(gg);          \
                float hn = sigm(go) * tanh_(cn);                             \
                cnv[r] = cn;                                                 \
                int row = mi * 16 + kg * 4 + r;                              \
                h0new[row * 256 + (col ^ ((row & 7) << 3))] = f2bf(hn);      \
            }                                                                \
            c0r[mi][(HALF)] = cnv;                                           \
            PIN_AGPR(c0r[mi][(HALF)]);                                       \
            _Pragma("unroll") for (int g = 0; g < 4; g++)                    \
                acc[mi][g] = f32x4{0.f, 0.f, 0.f, 0.f};                      \
        }                                                                    \
    }

#define EPIB(HALF)                                                           \
    {                                                                        \
        int col = w * 32 + (HALF) * 16 + lrow;                               \
        float bI = biasL1[(HALF) * 4 + 0];                                   \
        float bF = biasL1[(HALF) * 4 + 1];                                   \
        float bG = biasL1[(HALF) * 4 + 2];                                   \
        float bO = biasL1[(HALF) * 4 + 3];                                   \
        _Pragma("unroll") for (int mi = 0; mi < 2; mi++) {                   \
            f32x4 cp = c1r[mi][(HALF)];                                      \
            f32x4 cnv;                                                       \
            _Pragma("unroll") for (int r = 0; r < 4; r++) {                  \
                float gi = acc[mi][0][r] + bI;                               \
                float gf = acc[mi][1][r] + bF;                               \
                float gg = acc[mi][2][r] + bG;                               \
                float go = acc[mi][3][r] + bO;                               \
                float cn = sigm(gf) * cp[r] + sigm(gi) * tanh_(gg);          \
                float hn = sigm(go) * tanh_(cn);                             \
                cnv[r] = cn;                                                 \
                int row = mi * 16 + kg * 4 + r;                              \
                h1new[row * 256 + (col ^ ((row & 7) << 3))] = f2bf(hn);      \
            }                                                                \
            c1r[mi][(HALF)] = cnv;                                           \
            PIN_AGPR(c1r[mi][(HALF)]);                                       \
            _Pragma("unroll") for (int g = 0; g < 4; g++)                    \
                acc[mi][g] = f32x4{0.f, 0.f, 0.f, 0.f};                      \
        }                                                                    \
    }

__global__ __launch_bounds__(512, 1) void lstm_persistent(
    const unsigned short* __restrict__ Wp0, const unsigned short* __restrict__ Wp1,
    const unsigned short* __restrict__ Wcomb,
    const u16x4* __restrict__ gxs4, const float* __restrict__ biasC,
    const float* __restrict__ W_op, const float* __restrict__ b_op,
    float* __restrict__ out_final)
{
    __shared__ unsigned short lds[66560];   // 130 KB

    const int blk  = blockIdx.x;            // rows blk*32 .. +32
    const int w    = threadIdx.x >> 6;
    const int lane = threadIdx.x & 63;
    const int lrow = lane & 15;
    const int kg   = lane >> 4;
    const int sw   = (lrow & 7) << 3;       // A-frag k-swizzle

    // W_op copy into LDS (keeps proj off vmcnt in the hot loop)
    float* wopl = (float*)&lds[65536];
    wopl[threadIdx.x] = W_op[threadIdx.x];

    // gx preload — PARKED IN AGPRs (32 regs off the arch-VGPR pool)
    u16x4 gxr[16];
    {
        const u16x4* gxw = gxs4 + (size_t)(blk * 8 + w) * 16 * 64;
#pragma unroll
        for (int j = 0; j < 16; j++) {
            gxr[j] = gxw[j * 64 + lane];
            PIN_AGPR(gxr[j]);
        }
    }
    // L1 biases — PARKED IN AGPRs (8 regs off the arch-VGPR pool)
    float biasL1[8];
#pragma unroll
    for (int ni2 = 0; ni2 < 2; ni2++)
#pragma unroll
        for (int g = 0; g < 4; g++) {
            biasL1[ni2 * 4 + g] = biasC[g * 256 + w * 32 + ni2 * 16 + lrow];
            PIN_AGPR(biasL1[ni2 * 4 + g]);
        }

    f32x4 c0r[2][2], c1r[2][2];
#pragma unroll
    for (int mi = 0; mi < 2; mi++)
#pragma unroll
        for (int ni2 = 0; ni2 < 2; ni2++) {
            c0r[mi][ni2] = f32x4{0.f, 0.f, 0.f, 0.f};
            c1r[mi][ni2] = f32x4{0.f, 0.f, 0.f, 0.f};
            PIN_AGPR(c0r[mi][ni2]);
            PIN_AGPR(c1r[mi][ni2]);
        }

    const unsigned short* wc = Wcomb + (size_t)w * 98304 + (size_t)lane * 8;
    unsigned short* wbuf_base = &lds[32768 + w * 4096];        // wave-uniform dest
    const unsigned short* wbufL = wbuf_base + lane * 8;        // per-lane read

    const int prow = threadIdx.x >> 4;
    const int pseg = threadIdx.x & 15;
    const int psw  = (prow & 7) << 3;

    f32x4 acc[2][4];
#pragma unroll
    for (int mi = 0; mi < 2; mi++)
#pragma unroll
        for (int g = 0; g < 4; g++) acc[mi][g] = f32x4{0.f, 0.f, 0.f, 0.f};

    // ================= i = 0 : h0[0] from gx only =================
    {
        unsigned short* h0new = lds;  // buffer 0
        EPIA(0);
        EPIA(1);
    }
    __syncthreads();

    // ================= i = 1 : direct A + direct B-init =================
    {
        const unsigned short* wp0w = Wp0 + (size_t)w * 32768 + (size_t)lane * 8;
        const unsigned short* wp1w = Wp1 + (size_t)w * 65536 + (size_t)lane * 8;
        unsigned short* h0new = lds + 8192;       // h0[1]
        const unsigned short* h0prev = lds;       // h0[0]
#pragma unroll
        for (int half = 0; half < 2; half++) {
#pragma unroll
            for (int kbi = 0; kbi < 8; kbi++) {
                short8 a0, a1, b[4];
                int k = (kbi * 32 + kg * 8) ^ sw;
                a0 = *(const short8*)&h0prev[lrow * 256 + k];
                a1 = *(const short8*)&h0prev[(16 + lrow) * 256 + k];
#pragma unroll
                for (int g = 0; g < 4; g++)
                    b[g] = *(const short8*)&wp0w[(size_t)(((half * 4 + g) * 8 + kbi) * 512)];
#pragma unroll
                for (int g = 0; g < 4; g++) {
                    acc[0][g] = MFMA_BF16(a0, b[g], acc[0][g]);
                    acc[1][g] = MFMA_BF16(a1, b[g], acc[1][g]);
                }
            }
            if (half == 0) { EPIA(0); } else { EPIA(1); }
        }
        // B-init: h1[0], c1 = i-gate * g-gate only
        unsigned short* h1new = lds + 16384;      // h1[0] -> ping 0
#pragma unroll
        for (int half = 0; half < 2; half++) {
#pragma unroll
            for (int kbi = 0; kbi < 8; kbi++) {
                short8 a0, a1, b[4];
                int k = (kbi * 32 + kg * 8) ^ sw;
                a0 = *(const short8*)&h0prev[lrow * 256 + k];
                a1 = *(const short8*)&h0prev[(16 + lrow) * 256 + k];
#pragma unroll
                for (int g = 0; g < 4; g++)
                    b[g] = *(const short8*)&wp1w[(size_t)(((half * 4 + g) * 16 + kbi) * 512)];
#pragma unroll
                for (int g = 0; g < 4; g++) {
                    acc[0][g] = MFMA_BF16(a0, b[g], acc[0][g]);
                    acc[1][g] = MFMA_BF16(a1, b[g], acc[1][g]);
                }
            }
            int col = w * 32 + half * 16 + lrow;
#pragma unroll
            for (int mi = 0; mi < 2; mi++) {
                f32x4 cnv;
#pragma unroll
                for (int r = 0; r < 4; r++) {
                    float gi = acc[mi][0][r] + biasL1[half * 4 + 0];
                    float gg = acc[mi][2][r] + biasL1[half * 4 + 2];
                    float go = acc[mi][3][r] + biasL1[half * 4 + 3];
                    float cn = sigm(gi) * tanh_(gg);
                    float hn = sigm(go) * tanh_(cn);
                    cnv[r] = cn;
                    int row = mi * 16 + kg * 4 + r;
                    h1new[row * 256 + (col ^ ((row & 7) << 3))] = f2bf(hn);
                }
                c1r[mi][half] = cnv;
                PIN_AGPR(c1r[mi][half]);
#pragma unroll
                for (int g = 0; g < 4; g++) acc[mi][g] = f32x4{0.f, 0.f, 0.f, 0.f};
            }
        }
    }
    __syncthreads();

    // ================= i = 2..29 : streamed full iterations =================
    for (int i = 2; i <= 29; ++i) {
        unsigned short* h0new = lds + (i & 1) * 8192;
        const unsigned short* h0prev = lds + ((i - 1) & 1) * 8192;
        const unsigned short* h1prev = lds + 16384 + (i & 1) * 8192;
        unsigned short* h1new = lds + 16384 + ((i - 1) & 1) * 8192;

        STG(0); STG(1); STG(2);

        short8 a0, a1;
        // ---- phase A: chunks 0..31 ----
#pragma unroll
        for (int s = 0; s < 32; s++) {
            const int kbi = (s >> 1) & 7;
            const int g0 = (s & 1) * 2;
            if ((s & 1) == 0) {
                int k = (kbi * 32 + kg * 8) ^ sw;
                a0 = *(const short8*)&h0prev[lrow * 256 + k];
                a1 = *(const short8*)&h0prev[(16 + lrow) * 256 + k];
            }
            asm volatile("s_waitcnt vmcnt(4)" ::: "memory");
            short8 b0 = *(const short8*)(wbufL + (s & 3) * 1024);
            short8 b1 = *(const short8*)(wbufL + (s & 3) * 1024 + 512);
            acc[0][g0]     = MFMA_BF16(a0, b0, acc[0][g0]);
            acc[1][g0]     = MFMA_BF16(a1, b0, acc[1][g0]);
            acc[0][g0 + 1] = MFMA_BF16(a0, b1, acc[0][g0 + 1]);
            acc[1][g0 + 1] = MFMA_BF16(a1, b1, acc[1][g0 + 1]);
            STG(s + 3);
            if (s == 15) { EPIA(0); }
        }
        EPIA(1);

        // ---- phase B: chunks 32..95 ----
#pragma unroll
        for (int s = 32; s < 96; s++) {
            const int t = s - 32;
            const int kk = (t >> 1) & 15;
            const int g0 = (t & 1) * 2;
            if ((t & 1) == 0) {
                const unsigned short* hsrc = (kk < 8) ? h0prev : h1prev;
                int k = ((kk & 7) * 32 + kg * 8) ^ sw;
                a0 = *(const short8*)&hsrc[lrow * 256 + k];
                a1 = *(const short8*)&hsrc[(16 + lrow) * 256 + k];
            }
            if (s <= 93)      asm volatile("s_waitcnt vmcnt(4)" ::: "memory");
            else if (s == 94) asm volatile("s_waitcnt vmcnt(2)" ::: "memory");
            else              asm volatile("s_waitcnt vmcnt(0)" ::: "memory");
            short8 b0 = *(const short8*)(wbufL + (s & 3) * 1024);
            short8 b1 = *(const short8*)(wbufL + (s & 3) * 1024 + 512);
            acc[0][g0]     = MFMA_BF16(a0, b0, acc[0][g0]);
            acc[1][g0]     = MFMA_BF16(a1, b0, acc[1][g0]);
            acc[0][g0 + 1] = MFMA_BF16(a0, b1, acc[0][g0 + 1]);
            acc[1][g0 + 1] = MFMA_BF16(a1, b1, acc[1][g0 + 1]);
            if (s + 3 < 96) STG(s + 3);
            if (t == 31) { EPIB(0); }
        }
        EPIB(1);

        // ---- out-projection: t = i-2 (reads h1[i-2]) ----
        {
            const unsigned short* h1t = lds + 16384 + (i & 1) * 8192;
            float p0 = 0.f, p1 = 0.f;
#pragma unroll
            for (int q = 0; q < 2; q++) {
                int col0 = pseg * 16 + q * 8;
                short8 hv = *(const short8*)&h1t[prow * 256 + (col0 ^ psw)];
#pragma unroll
                for (int e = 0; e < 8; e++) {
                    float h = bf2f((unsigned short)hv[e]);
                    p0 += h * wopl[col0 + e];
                    p1 += h * wopl[256 + col0 + e];
                }
            }
#pragma unroll
            for (int sfl = 1; sfl < 16; sfl <<= 1) {
                p0 += __shfl_xor(p0, sfl, 64);
                p1 += __shfl_xor(p1, sfl, 64);
            }
            if (pseg == 0) {
                int grow = blk * 32 + prow;
                int t = i - 2;
                out_final[((size_t)grow * TT + t) * 2 + 0] = p0 + b_op[0];
                out_final[((size_t)grow * TT + t) * 2 + 1] = p1 + b_op[1];
            }
        }
        __syncthreads();
    }

    // ================= i = 30 : direct B + proj(28) =================
    {
        const int i = 30;
        const unsigned short* wp1w = Wp1 + (size_t)w * 65536 + (size_t)lane * 8;
        const unsigned short* h0prev = lds + ((i - 1) & 1) * 8192;
        const unsigned short* h1prev = lds + 16384 + (i & 1) * 8192;
        unsigned short* h1new = lds + 16384 + ((i - 1) & 1) * 8192;
#pragma unroll
        for (int half = 0; half < 2; half++) {
#pragma unroll
            for (int kk = 0; kk < 16; kk++) {
                short8 a0, a1, b[4];
                const unsigned short* hsrc = (kk < 8) ? h0prev : h1prev;
                int k = ((kk & 7) * 32 + kg * 8) ^ sw;
                a0 = *(const short8*)&hsrc[lrow * 256 + k];
                a1 = *(const short8*)&hsrc[(16 + lrow) * 256 + k];
#pragma unroll
                for (int g = 0; g < 4; g++)
                    b[g] = *(const short8*)&wp1w[(size_t)(((half * 4 + g) * 16 + kk) * 512)];
#pragma unroll
                for (int g = 0; g < 4; g++) {
                    acc[0][g] = MFMA_BF16(a0, b[g], acc[0][g]);
                    acc[1][g] = MFMA_BF16(a1, b[g], acc[1][g]);
                }
            }
            if (half == 0) { EPIB(0); } else { EPIB(1); }
        }
        {
            const unsigned short* h1t = lds + 16384 + (i & 1) * 8192;
            float p0 = 0.f, p1 = 0.f;
#pragma unroll
            for (int q = 0; q < 2; q++) {
                int col0 = pseg * 16 + q * 8;
                short8 hv = *(const short8*)&h1t[prow * 256 + (col0 ^ psw)];
#pragma unroll
                for (int e = 0; e < 8; e++) {
                    float h = bf2f((unsigned short)hv[e]);
                    p0 += h * wopl[col0 + e];
                    p1 += h * wopl[256 + col0 + e];
                }
            }
#pragma unroll
            for (int sfl = 1; sfl < 16; sfl <<= 1) {
                p0 += __shfl_xor(p0, sfl, 64);
                p1 += __shfl_xor(p1, sfl, 64);
            }
            if (pseg == 0) {
                int grow = blk * 32 + prow;
                out_final[((size_t)grow * TT + 28) * 2 + 0] = p0 + b_op[0];
                out_final[((size_t)grow * TT + 28) * 2 + 1] = p1 + b_op[1];
            }
        }
    }
    __syncthreads();

    // ================= i = 31 : proj(29) =================
    {
        const unsigned short* h1t = lds + 16384 + (31 & 1) * 8192;
        float p0 = 0.f, p1 = 0.f;
#pragma unroll
        for (int q = 0; q < 2; q++) {
            int col0 = pseg * 16 + q * 8;
            short8 hv = *(const short8*)&h1t[prow * 256 + (col0 ^ psw)];
#pragma unroll
            for (int e = 0; e < 8; e++) {
                float h = bf2f((unsigned short)hv[e]);
                p0 += h * wopl[col0 + e];
                p1 += h * wopl[256 + col0 + e];
            }
        }
#pragma unroll
        for (int sfl = 1; sfl < 16; sfl <<= 1) {
            p0 += __shfl_xor(p0, sfl, 64);
            p1 += __shfl_xor(p1, sfl, 64);
        }
        if (pseg == 0) {
            int grow = blk * 32 + prow;
            out_final[((size_t)grow * TT + 29) * 2 + 0] = p0 + b_op[0];
            out_final[((size_t)grow * TT + 29) * 2 + 1] = p1 + b_op[1];
        }
    }
}

// ---------------- host ----------------
extern "C" void kernel_launch(void* const* d_in, const int* in_sizes, int n_in,
                              void* d_out, int out_size, void* d_ws, size_t ws_size,
                              hipStream_t stream)
{
    const float* obs    = (const float*)d_in[0];
    const float* lane   = (const float*)d_in[1];
    const float* ds     = (const float*)d_in[3];
    const float* W_hid  = (const float*)d_in[4];
    const float* b_hid  = (const float*)d_in[5];
    const float* W_ep   = (const float*)d_in[6];
    const float* b_ep   = (const float*)d_in[7];
    const float* W_conf = (const float*)d_in[8];
    const float* b_conf = (const float*)d_in[9];
    const float* W_ih0  = (const float*)d_in[10];
    const float* W_hh0  = (const float*)d_in[11];
    const float* b_ih0  = (const float*)d_in[12];
    const float* b_hh0  = (const float*)d_in[13];
    const float* W_ih1  = (const float*)d_in[14];
    const float* W_hh1  = (const float*)d_in[15];
    const float* b_ih1  = (const float*)d_in[16];
    const float* b_hh1  = (const float*)d_in[17];
    const float* W_op   = (const float*)d_in[18];
    const float* b_op   = (const float*)d_in[19];

    float* out_final = (float*)d_out;           // [6144*30*2]
    float* out_conf  = out_final + 368640;      // [6144]
    float* out_ep    = out_conf + 6144;         // [6144*2]

    char* ws = (char*)d_ws;
    size_t off = 0;
    auto alloc = [&](size_t bytes) -> void* {
        void* p = ws + off;
        off += (bytes + 255) & ~(size_t)255;
        return p;
    };
    unsigned short* Whid_b = (unsigned short*)alloc(65536 * 2);
    unsigned short* Wih0_b = (unsigned short*)alloc(262144 * 2);
    unsigned short* Wp0    = (unsigned short*)alloc(262144 * 2);
    unsigned short* Wp1    = (unsigned short*)alloc(524288 * 2);
    float*          biasC  = (float*)alloc(1024 * 4);
    unsigned short* Wcomb  = (unsigned short*)alloc((size_t)786432 * 2);
    unsigned short* comb_b = (unsigned short*)alloc(1572864 * 2);
    unsigned short* hid_b  = (unsigned short*)alloc(1572864 * 2);
    float* ep_buf = (float*)alloc(12288 * 4);
    u16x4* gxs4   = (u16x4*)alloc((size_t)1572864 * 8);

    cvt_weights<<<4356, 256, 0, stream>>>(W_hid, W_ih0, W_hh0, W_ih1, W_hh1,
                                          b_ih1, b_hh1,
                                          Whid_b, Wih0_b, Wp0, Wp1, biasC);
    pack_comb<<<3072, 256, 0, stream>>>(Wp0, Wp1, Wcomb);
    build_combined<<<6144, 256, 0, stream>>>(obs, lane, ds, comb_b);
    gemm_hidden<<<96, 256, 0, stream>>>(comb_b, Whid_b, b_hid, hid_b);
    head_kernel<<<24, 256, 0, stream>>>(hid_b, W_ep, b_ep, W_conf, b_conf,
                                        out_conf, out_ep, ep_buf);
    dim3 g2(96, 4);
    gemm_gx0<<<g2, 256, 0, stream>>>(hid_b, Wih0_b, W_ih0, b_ih0, b_hh0, ep_buf, gxs4);

    lstm_persistent<<<192, 512, 0, stream>>>(Wp0, Wp1, Wcomb, gxs4, biasC,
                                             W_op, b_op, out_final);
}

// Round 18
// 916.716 us; speedup vs baseline: 1.6394x; 1.5284x over previous
//
#include <hip/hip_runtime.h>

// ---------------- types & helpers ----------------
typedef short short8 __attribute__((ext_vector_type(8)));
typedef float f32x4 __attribute__((ext_vector_type(4)));
typedef unsigned short u16x4 __attribute__((ext_vector_type(4)));

#define MFMA_BF16(a, b, c) __builtin_amdgcn_mfma_f32_16x16x32_bf16((a), (b), (c), 0, 0, 0)
#define PIN_AGPR(x) asm volatile("" : "+a"(x))

// async global->LDS, 16B per lane (vmcnt-tracked, NO VGPR destination).
__device__ __forceinline__ void gload_lds16(const void* g, void* l) {
    __builtin_amdgcn_global_load_lds(
        (const __attribute__((address_space(1))) unsigned int*)g,
        (__attribute__((address_space(3))) unsigned int*)l, 16, 0, 0);
}

__device__ __forceinline__ float bf2f(unsigned short u) {
    return __uint_as_float(((unsigned)u) << 16);
}
__device__ __forceinline__ unsigned short f2bf(float f) {
    unsigned u = __float_as_uint(f);
    u += 0x7FFFu + ((u >> 16) & 1u);  // round-to-nearest-even
    return (unsigned short)(u >> 16);
}
// NOTE (r14 vs r16 A/B): full-precision divides here are INTENTIONAL. The
// rcp-based variant cut VALU busy 39%->14% but tripled FETCH (485MB->1.3GB,
// L2 hit-rate drop from epilogue-ILP/regalloc coupling) and was net SLOWER
// (918 -> 1400us). Divides serialize the epilogue and keep Wcomb L2-resident.
__device__ __forceinline__ float sigm(float x) { return 1.0f / (1.0f + __expf(-x)); }
__device__ __forceinline__ float tanh_(float x) {
    float e = __expf(-2.0f * fabsf(x));
    float t = (1.0f - e) / (1.0f + e);
    return copysignf(t, x);
}

#define TT 30

// ---------------- weight conversion / packing ----------------
// Regions: Whid_b 65536 | Wih0_b 262144 | Wp0 262144 (frag-packed W_hh0) |
//   Wp1 524288 (frag-packed [W_ih1|W_hh1]) | biasC 1024
__global__ __launch_bounds__(256) void cvt_weights(
    const float* __restrict__ W_hid, const float* __restrict__ W_ih0,
    const float* __restrict__ W_hh0, const float* __restrict__ W_ih1,
    const float* __restrict__ W_hh1, const float* __restrict__ b_ih1,
    const float* __restrict__ b_hh1,
    unsigned short* __restrict__ Whid_b, unsigned short* __restrict__ Wih0_b,
    unsigned short* __restrict__ Wp0, unsigned short* __restrict__ Wp1,
    float* __restrict__ biasC)
{
    int idx = blockIdx.x * 256 + threadIdx.x;
    if (idx < 65536) { Whid_b[idx] = f2bf(W_hid[idx]); return; }
    idx -= 65536;
    if (idx < 262144) {
        int gc = idx >> 8, k = idx & 255;
        Wih0_b[idx] = f2bf(W_ih0[gc * 258 + k]);
        return;
    }
    idx -= 262144;
    if (idx < 262144) {
        int p = idx;
        int e = p & 7, L = (p >> 3) & 63, kbi = (p >> 9) & 7, n = p >> 12;
        int h16 = n >> 2, g = n & 3;
        int j = g * 256 + h16 * 16 + (L & 15);
        int k = kbi * 32 + (L >> 4) * 8 + e;
        Wp0[p] = f2bf(W_hh0[j * 256 + k]);
        return;
    }
    idx -= 262144;
    if (idx < 524288) {
        int p = idx;
        int e = p & 7, L = (p >> 3) & 63, kbi = (p >> 9) & 15, n = p >> 13;
        int h16 = n >> 2, g = n & 3;
        int j = g * 256 + h16 * 16 + (L & 15);
        int k = kbi * 32 + (L >> 4) * 8 + e;
        float v = (k < 256) ? W_ih1[j * 256 + k] : W_hh1[j * 256 + (k - 256)];
        Wp1[p] = f2bf(v);
        return;
    }
    idx -= 524288;
    if (idx < 1024) biasC[idx] = b_ih1[idx] + b_hh1[idx];
}

// ---------------- pack the per-wave SEQUENTIAL stream Wcomb ----------------
// Wcomb[w][s][g2][L][e]: sub-chunk s (0..95) = 2 gate-slices of 512 ushorts.
//  s<32  (phase A): half=s>>4, kbi=(s>>1)&7, gp=s&1, n=half*4+gp*2+g2 -> Wp0
//  s>=32 (phase B): t=s-32: half=t>>5, kk=(t>>1)&15, gp=t&1           -> Wp1
__global__ __launch_bounds__(256) void pack_comb(
    const unsigned short* __restrict__ Wp0, const unsigned short* __restrict__ Wp1,
    unsigned short* __restrict__ Wcomb)
{
    int idx = blockIdx.x * 256 + threadIdx.x;   // < 786432
    int w = idx / 98304;
    int r = idx - w * 98304;
    int s = r >> 10;
    int q = r & 1023;
    int g2 = q >> 9;
    int le = q & 511;
    unsigned short v;
    if (s < 32) {
        int half = s >> 4, kbi = (s >> 1) & 7, gp = s & 1;
        int nl = half * 4 + gp * 2 + g2;
        v = Wp0[(size_t)(w * 8 + nl) * 4096 + kbi * 512 + le];
    } else {
        int t = s - 32;
        int half = t >> 5, kk = (t >> 1) & 15, gp = t & 1;
        int nl = half * 4 + gp * 2 + g2;
        v = Wp1[(size_t)(w * 8 + nl) * 8192 + kk * 512 + le];
    }
    Wcomb[idx] = v;
}

// combined[n, c] : c<128 obs[b], c<192 lane[b], else ds[kk]
__global__ __launch_bounds__(256) void build_combined(
    const float* __restrict__ obs, const float* __restrict__ lane,
    const float* __restrict__ ds, unsigned short* __restrict__ comb)
{
    int idx = blockIdx.x * 256 + threadIdx.x;  // < 6144*256
    int n = idx >> 8, c = idx & 255;
    int b = n / 6, kk = n - b * 6;
    float v;
    if (c < 128)      v = obs[b * 128 + c];
    else if (c < 192) v = lane[b * 64 + (c - 128)];
    else              v = ds[kk * 64 + (c - 192)];
    comb[idx] = f2bf(v);
}

// ---------------- GEMM: hidden = leakyrelu(combined @ W_hid^T + b_hid) ----------------
__global__ __launch_bounds__(256) void gemm_hidden(
    const unsigned short* __restrict__ A, const unsigned short* __restrict__ B,
    const float* __restrict__ b_hid, unsigned short* __restrict__ hidden)
{
    int wid = threadIdx.x >> 6, lane = threadIdx.x & 63;
    int lrow = lane & 15, kg = lane >> 4;
    int r0 = blockIdx.x * 64;
    int c0 = wid * 64;
    f32x4 acc[4][4];
#pragma unroll
    for (int i = 0; i < 4; i++)
#pragma unroll
        for (int j = 0; j < 4; j++) acc[i][j] = f32x4{0.f, 0.f, 0.f, 0.f};

#pragma unroll
    for (int kb = 0; kb < 256; kb += 32) {
        int k = kb + kg * 8;
        short8 a[4], b[4];
#pragma unroll
        for (int mi = 0; mi < 4; mi++)
            a[mi] = *(const short8*)(A + (size_t)(r0 + mi * 16 + lrow) * 256 + k);
#pragma unroll
        for (int ni = 0; ni < 4; ni++)
            b[ni] = *(const short8*)(B + (size_t)(c0 + ni * 16 + lrow) * 256 + k);
#pragma unroll
        for (int mi = 0; mi < 4; mi++)
#pragma unroll
            for (int ni = 0; ni < 4; ni++)
                acc[mi][ni] = MFMA_BF16(a[mi], b[ni], acc[mi][ni]);
    }
#pragma unroll
    for (int mi = 0; mi < 4; mi++) {
#pragma unroll
        for (int ni = 0; ni < 4; ni++) {
            int col = c0 + ni * 16 + lrow;
            float bb = b_hid[col];
#pragma unroll
            for (int r = 0; r < 4; r++) {
                int row = r0 + mi * 16 + kg * 4 + r;
                float x = acc[mi][ni][r] + bb;
                x = x >= 0.f ? x : 0.1f * x;
                hidden[(size_t)row * 256 + col] = f2bf(x);
            }
        }
    }
}

// ---------------- endpoint / conf head (thread per row) ----------------
__global__ __launch_bounds__(256) void head_kernel(
    const unsigned short* __restrict__ hidden, const float* __restrict__ W_ep,
    const float* __restrict__ b_ep, const float* __restrict__ W_conf,
    const float* __restrict__ b_conf, float* __restrict__ out_conf,
    float* __restrict__ out_ep, float* __restrict__ ep_buf)
{
    int n = blockIdx.x * 256 + threadIdx.x;  // < 6144
    const unsigned short* hr = hidden + (size_t)n * 256;
    float e0 = 0.f, e1 = 0.f, cf = 0.f;
    for (int k = 0; k < 256; k += 8) {
        short8 hv = *(const short8*)(hr + k);
#pragma unroll
        for (int i = 0; i < 8; i++) {
            float h = bf2f((unsigned short)hv[i]);
            e0 += h * W_ep[k + i];
            e1 += h * W_ep[256 + k + i];
            cf += h * W_conf[k + i];
        }
    }
    e0 += b_ep[0]; e1 += b_ep[1]; cf += b_conf[0];
    out_conf[n] = cf;
    out_ep[2 * n] = e0; out_ep[2 * n + 1] = e1;
    ep_buf[2 * n] = e0; ep_buf[2 * n + 1] = e1;
}

// ---------------- GEMM: gx0 (b_ih0+b_hh0 folded, ep rank-2), bf16 frag-layout out ----
__global__ __launch_bounds__(256) void gemm_gx0(
    const unsigned short* __restrict__ A, const unsigned short* __restrict__ B,
    const float* __restrict__ W_ih0f, const float* __restrict__ b_ih0,
    const float* __restrict__ b_hh0, const float* __restrict__ ep_buf,
    u16x4* __restrict__ gxs4)
{
    int wid = threadIdx.x >> 6, lane = threadIdx.x & 63;
    int lrow = lane & 15, kg = lane >> 4;
    int r0 = blockIdx.x * 64;
    int g  = blockIdx.y;                   // gate
    int c0 = g * 256 + wid * 64;
    f32x4 acc[4][4];
#pragma unroll
    for (int i = 0; i < 4; i++)
#pragma unroll
        for (int j = 0; j < 4; j++) acc[i][j] = f32x4{0.f, 0.f, 0.f, 0.f};

#pragma unroll
    for (int kb = 0; kb < 256; kb += 32) {
        int k = kb + kg * 8;
        short8 a[4], b[4];
#pragma unroll
        for (int mi = 0; mi < 4; mi++)
            a[mi] = *(const short8*)(A + (size_t)(r0 + mi * 16 + lrow) * 256 + k);
#pragma unroll
        for (int ni = 0; ni < 4; ni++)
            b[ni] = *(const short8*)(B + (size_t)(c0 + ni * 16 + lrow) * 256 + k);
#pragma unroll
        for (int mi = 0; mi < 4; mi++)
#pragma unroll
            for (int ni = 0; ni < 4; ni++)
                acc[mi][ni] = MFMA_BF16(a[mi], b[ni], acc[mi][ni]);
    }
#pragma unroll
    for (int mi = 0; mi < 4; mi++) {
#pragma unroll
        for (int ni = 0; ni < 4; ni++) {
            int gc = c0 + ni * 16 + lrow;
            float w256 = W_ih0f[(size_t)gc * 258 + 256];
            float w257 = W_ih0f[(size_t)gc * 258 + 257];
            float bb = b_ih0[gc] + b_hh0[gc];
            int h16 = wid * 4 + ni;
            int wv = h16 >> 1, ni2 = h16 & 1;
            int pb = blockIdx.x * 2 + (mi >> 1);
            int idx16 = ((mi & 1) * 2 + ni2) * 4 + g;
            u16x4 pv;
#pragma unroll
            for (int r = 0; r < 4; r++) {
                int row = r0 + mi * 16 + kg * 4 + r;
                float v = acc[mi][ni][r] + bb + ep_buf[2 * row] * w256 + ep_buf[2 * row + 1] * w257;
                pv[r] = f2bf(v);
            }
            gxs4[(size_t)((pb * 8 + wv) * 16 + idx16) * 64 + lane] = pv;
        }
    }
}

// ---------------- persistent 30-step LSTM: counted-vmcnt weight stream --------
// 192 blocks x 512 threads (8 waves). Block owns 32 rows. Wave w: hcols [w*32,+32).
// EXACT r14 configuration (best measured: 918us). Weights stream global->LDS as
// ONE sequential 96x2KB-chunk stream per iter (Wcomb), 4-buffer ring, 3 chunks
// ahead, s_waitcnt vmcnt(4) per chunk (T4-counted, never 0 until tail).
// In-flight weights use ZERO VGPRs. LDS 130KB: h0 pp @0/16KB, h1 pp @32/48KB
// (XOR swizzle col^((row&7)<<3)), ring bufs @64KB+w*8KB, W_op copy @128KB.
// gx in 16 regs; c AGPR-pinned; biasL1 in 8 regs; NO other vmem in hot loop.
#define STG(sv)                                                              \
    {                                                                        \
        const unsigned short* _s = wc + (size_t)(sv) * 1024;                 \
        unsigned short* _d = wbuf_base + ((sv) & 3) * 1024;                  \
        gload_lds16(_s, _d);                                                 \
        gload_lds16(_s + 512, _d + 512);                                     \
    }

#define EPIA(HALF)                                                           \
    {                                                                        \
        int col = w * 32 + (HALF) * 16 + lrow;                               \
        _Pragma("unroll") for (int mi = 0; mi < 2; mi++) {                   \
            u16x4 gI = gxr[(mi * 2 + (HALF)) * 4 + 0];                       \
            u16x4 gF = gxr[(mi * 2 + (HALF)) * 4 + 1];                       \
            u16x4 gG = gxr[(mi * 2 + (HALF)) * 4 + 2];                       \
            u16x4 gO = gxr[(mi * 2 + (HALF)) * 4 + 3];                       \
            f32x4 cp = c0r[mi][(HALF)];                                      \
            f32x4 cnv;                                                       \
            _Pragma("unroll") for (int r = 0; r < 4; r++) {                  \
                float gi = acc[mi][0][r] + bf2f(gI[r]);                      \
                float gf = acc[mi][1][r] + bf2f(gF[r]);                      \
                float gg = acc[mi][2][r] + bf2f(gG[r]);                      \
                float go = acc[mi][3][r] + bf2f(gO[r]);                      \
                float cn = sigm(gf) * cp[r] + sigm(gi) * tanh_(gg);          \
                float hn = sigm(go) * tanh_(cn);                             \
                cnv[r] = cn;                                                 \
                int row = mi * 16 + kg * 4 + r;                              \
                h0new[row * 256 + (col ^ ((row & 7) << 3))] = f2bf(hn);      \
            }                                                                \
            c0r[mi][(HALF)] = cnv;                                           \
            PIN_AGPR(c0r[mi][(HALF)]);                                       \
            _Pragma("unroll") for (int g = 0; g < 4; g++)                    \
                acc[mi][g] = f32x4{0.f, 0.f, 0.f, 0.f};                      \
        }                                                                    \
    }

#define EPIB(HALF)                                                           \
    {                                                                        \
        int col = w * 32 + (HALF) * 16 + lrow;                               \
        _Pragma("unroll") for (int mi = 0; mi < 2; mi++) {                   \
            f32x4 cp = c1r[mi][(HALF)];                                      \
            f32x4 cnv;                                                       \
            _Pragma("unroll") for (int r = 0; r < 4; r++) {                  \
                float gi = acc[mi][0][r] + biasL1[(HALF) * 4 + 0];           \
                float gf = acc[mi][1][r] + biasL1[(HALF) * 4 + 1];           \
                float gg = acc[mi][2][r] + biasL1[(HALF) * 4 + 2];           \
                float go = acc[mi][3][r] + biasL1[(HALF) * 4 + 3];           \
                float cn = sigm(gf) * cp[r] + sigm(gi) * tanh_(gg);          \
                float hn = sigm(go) * tanh_(cn);                             \
                cnv[r] = cn;                                                 \
                int row = mi * 16 + kg * 4 + r;                              \
                h1new[row * 256 + (col ^ ((row & 7) << 3))] = f2bf(hn);      \
            }                                                                \
            c1r[mi][(HALF)] = cnv;                                           \
            PIN_AGPR(c1r[mi][(HALF)]);                                       \
            _Pragma("unroll") for (int g = 0; g < 4; g++)                    \
                acc[mi][g] = f32x4{0.f, 0.f, 0.f, 0.f};                      \
        }                                                                    \
    }

__global__ __launch_bounds__(512, 1) void lstm_persistent(
    const unsigned short* __restrict__ Wp0, const unsigned short* __restrict__ Wp1,
    const unsigned short* __restrict__ Wcomb,
    const u16x4* __restrict__ gxs4, const float* __restrict__ biasC,
    const float* __restrict__ W_op, const float* __restrict__ b_op,
    float* __restrict__ out_final)
{
    __shared__ unsigned short lds[66560];   // 130 KB

    const int blk  = blockIdx.x;            // rows blk*32 .. +32
    const int w    = threadIdx.x >> 6;
    const int lane = threadIdx.x & 63;
    const int lrow = lane & 15;
    const int kg   = lane >> 4;
    const int sw   = (lrow & 7) << 3;       // A-frag k-swizzle

    // W_op copy into LDS (keeps proj off vmcnt in the hot loop)
    float* wopl = (float*)&lds[65536];
    wopl[threadIdx.x] = W_op[threadIdx.x];

    // gx preload into registers — 16 VGPR
    u16x4 gxr[16];
    {
        const u16x4* gxw = gxs4 + (size_t)(blk * 8 + w) * 16 * 64;
#pragma unroll
        for (int j = 0; j < 16; j++) gxr[j] = gxw[j * 64 + lane];
    }
    // L1 biases in 8 regs (keeps them off vmcnt in the hot loop)
    float biasL1[8];
#pragma unroll
    for (int ni2 = 0; ni2 < 2; ni2++)
#pragma unroll
        for (int g = 0; g < 4; g++)
            biasL1[ni2 * 4 + g] = biasC[g * 256 + w * 32 + ni2 * 16 + lrow];

    f32x4 c0r[2][2], c1r[2][2];
#pragma unroll
    for (int mi = 0; mi < 2; mi++)
#pragma unroll
        for (int ni2 = 0; ni2 < 2; ni2++) {
            c0r[mi][ni2] = f32x4{0.f, 0.f, 0.f, 0.f};
            c1r[mi][ni2] = f32x4{0.f, 0.f, 0.f, 0.f};
            PIN_AGPR(c0r[mi][ni2]);
            PIN_AGPR(c1r[mi][ni2]);
        }

    const unsigned short* wc = Wcomb + (size_t)w * 98304 + (size_t)lane * 8;
    unsigned short* wbuf_base = &lds[32768 + w * 4096];        // wave-uniform dest
    const unsigned short* wbufL = wbuf_base + lane * 8;        // per-lane read
    const unsigned short* wp0w = Wp0 + (size_t)w * 32768 + (size_t)lane * 8;
    const unsigned short* wp1w = Wp1 + (size_t)w * 65536 + (size_t)lane * 8;

    const int prow = threadIdx.x >> 4;
    const int pseg = threadIdx.x & 15;
    const int psw  = (prow & 7) << 3;

    f32x4 acc[2][4];
#pragma unroll
    for (int mi = 0; mi < 2; mi++)
#pragma unroll
        for (int g = 0; g < 4; g++) acc[mi][g] = f32x4{0.f, 0.f, 0.f, 0.f};

    // ================= i = 0 : h0[0] from gx only =================
    {
        unsigned short* h0new = lds;  // buffer 0
        EPIA(0);
        EPIA(1);
    }
    __syncthreads();

    // ================= i = 1 : direct A + direct B-init =================
    {
        unsigned short* h0new = lds + 8192;       // h0[1]
        const unsigned short* h0prev = lds;       // h0[0]
#pragma unroll
        for (int half = 0; half < 2; half++) {
#pragma unroll
            for (int kbi = 0; kbi < 8; kbi++) {
                short8 a0, a1, b[4];
                int k = (kbi * 32 + kg * 8) ^ sw;
                a0 = *(const short8*)&h0prev[lrow * 256 + k];
                a1 = *(const short8*)&h0prev[(16 + lrow) * 256 + k];
#pragma unroll
                for (int g = 0; g < 4; g++)
                    b[g] = *(const short8*)&wp0w[(size_t)(((half * 4 + g) * 8 + kbi) * 512)];
#pragma unroll
                for (int g = 0; g < 4; g++) {
                    acc[0][g] = MFMA_BF16(a0, b[g], acc[0][g]);
                    acc[1][g] = MFMA_BF16(a1, b[g], acc[1][g]);
                }
            }
            if (half == 0) { EPIA(0); } else { EPIA(1); }
        }
        // B-init: h1[0], c1 = i-gate * g-gate only
        unsigned short* h1new = lds + 16384;      // h1[0] -> ping 0
#pragma unroll
        for (int half = 0; half < 2; half++) {
#pragma unroll
            for (int kbi = 0; kbi < 8; kbi++) {
                short8 a0, a1, b[4];
                int k = (kbi * 32 + kg * 8) ^ sw;
                a0 = *(const short8*)&h0prev[lrow * 256 + k];
                a1 = *(const short8*)&h0prev[(16 + lrow) * 256 + k];
#pragma unroll
                for (int g = 0; g < 4; g++)
                    b[g] = *(const short8*)&wp1w[(size_t)(((half * 4 + g) * 16 + kbi) * 512)];
#pragma unroll
                for (int g = 0; g < 4; g++) {
                    acc[0][g] = MFMA_BF16(a0, b[g], acc[0][g]);
                    acc[1][g] = MFMA_BF16(a1, b[g], acc[1][g]);
                }
            }
            int col = w * 32 + half * 16 + lrow;
#pragma unroll
            for (int mi = 0; mi < 2; mi++) {
                f32x4 cnv;
#pragma unroll
                for (int r = 0; r < 4; r++) {
                    float gi = acc[mi][0][r] + biasL1[half * 4 + 0];
                    float gg = acc[mi][2][r] + biasL1[half * 4 + 2];
                    float go = acc[mi][3][r] + biasL1[half * 4 + 3];
                    float cn = sigm(gi) * tanh_(gg);
                    float hn = sigm(go) * tanh_(cn);
                    cnv[r] = cn;
                    int row = mi * 16 + kg * 4 + r;
                    h1new[row * 256 + (col ^ ((row & 7) << 3))] = f2bf(hn);
                }
                c1r[mi][half] = cnv;
                PIN_AGPR(c1r[mi][half]);
#pragma unroll
                for (int g = 0; g < 4; g++) acc[mi][g] = f32x4{0.f, 0.f, 0.f, 0.f};
            }
        }
    }
    __syncthreads();

    // ================= i = 2..29 : streamed full iterations =================
    for (int i = 2; i <= 29; ++i) {
        unsigned short* h0new = lds + (i & 1) * 8192;
        const unsigned short* h0prev = lds + ((i - 1) & 1) * 8192;
        const unsigned short* h1prev = lds + 16384 + (i & 1) * 8192;
        unsigned short* h1new = lds + 16384 + ((i - 1) & 1) * 8192;

        STG(0); STG(1); STG(2);

        short8 a0, a1;
        // ---- phase A: chunks 0..31 ----
#pragma unroll
        for (int s = 0; s < 32; s++) {
            const int kbi = (s >> 1) & 7;
            const int g0 = (s & 1) * 2;
            if ((s & 1) == 0) {
                int k = (kbi * 32 + kg * 8) ^ sw;
                a0 = *(const short8*)&h0prev[lrow * 256 + k];
                a1 = *(const short8*)&h0prev[(16 + lrow) * 256 + k];
            }
            asm volatile("s_waitcnt vmcnt(4)" ::: "memory");
            short8 b0 = *(const short8*)(wbufL + (s & 3) * 1024);
            short8 b1 = *(const short8*)(wbufL + (s & 3) * 1024 + 512);
            acc[0][g0]     = MFMA_BF16(a0, b0, acc[0][g0]);
            acc[1][g0]     = MFMA_BF16(a1, b0, acc[1][g0]);
            acc[0][g0 + 1] = MFMA_BF16(a0, b1, acc[0][g0 + 1]);
            acc[1][g0 + 1] = MFMA_BF16(a1, b1, acc[1][g0 + 1]);
            STG(s + 3);
            if (s == 15) { EPIA(0); }
        }
        EPIA(1);

        // ---- phase B: chunks 32..95 ----
#pragma unroll
        for (int s = 32; s < 96; s++) {
            const int t = s - 32;
            const int kk = (t >> 1) & 15;
            const int g0 = (t & 1) * 2;
            if ((t & 1) == 0) {
                const unsigned short* hsrc = (kk < 8) ? h0prev : h1prev;
                int k = ((kk & 7) * 32 + kg * 8) ^ sw;
                a0 = *(const short8*)&hsrc[lrow * 256 + k];
                a1 = *(const short8*)&hsrc[(16 + lrow) * 256 + k];
            }
            if (s <= 93)      asm volatile("s_waitcnt vmcnt(4)" ::: "memory");
            else if (s == 94) asm volatile("s_waitcnt vmcnt(2)" ::: "memory");
            else              asm volatile("s_waitcnt vmcnt(0)" ::: "memory");
            short8 b0 = *(const short8*)(wbufL + (s & 3) * 1024);
            short8 b1 = *(const short8*)(wbufL + (s & 3) * 1024 + 512);
            acc[0][g0]     = MFMA_BF16(a0, b0, acc[0][g0]);
            acc[1][g0]     = MFMA_BF16(a1, b0, acc[1][g0]);
            acc[0][g0 + 1] = MFMA_BF16(a0, b1, acc[0][g0 + 1]);
            acc[1][g0 + 1] = MFMA_BF16(a1, b1, acc[1][g0 + 1]);
            if (s + 3 < 96) STG(s + 3);
            if (t == 31) { EPIB(0); }
        }
        EPIB(1);

        // ---- out-projection: t = i-2 (reads h1[i-2]) ----
        {
            const unsigned short* h1t = lds + 16384 + (i & 1) * 8192;
            float p0 = 0.f, p1 = 0.f;
#pragma unroll
            for (int q = 0; q < 2; q++) {
                int col0 = pseg * 16 + q * 8;
                short8 hv = *(const short8*)&h1t[prow * 256 + (col0 ^ psw)];
#pragma unroll
                for (int e = 0; e < 8; e++) {
                    float h = bf2f((unsigned short)hv[e]);
                    p0 += h * wopl[col0 + e];
                    p1 += h * wopl[256 + col0 + e];
                }
            }
#pragma unroll
            for (int sfl = 1; sfl < 16; sfl <<= 1) {
                p0 += __shfl_xor(p0, sfl, 64);
                p1 += __shfl_xor(p1, sfl, 64);
            }
            if (pseg == 0) {
                int grow = blk * 32 + prow;
                int t = i - 2;
                out_final[((size_t)grow * TT + t) * 2 + 0] = p0 + b_op[0];
                out_final[((size_t)grow * TT + t) * 2 + 1] = p1 + b_op[1];
            }
        }
        __syncthreads();
    }

    // ================= i = 30 : direct B + proj(28) =================
    {
        const int i = 30;
        const unsigned short* h0prev = lds + ((i - 1) & 1) * 8192;
        const unsigned short* h1prev = lds + 16384 + (i & 1) * 8192;
        unsigned short* h1new = lds + 16384 + ((i - 1) & 1) * 8192;
#pragma unroll
        for (int half = 0; half < 2; half++) {
#pragma unroll
            for (int kk = 0; kk < 16; kk++) {
                short8 a0, a1, b[4];
                const unsigned short* hsrc = (kk < 8) ? h0prev : h1prev;
                int k = ((kk & 7) * 32 + kg * 8) ^ sw;
                a0 = *(const short8*)&hsrc[lrow * 256 + k];
                a1 = *(const short8*)&hsrc[(16 + lrow) * 256 + k];
#pragma unroll
                for (int g = 0; g < 4; g++)
                    b[g] = *(const short8*)&wp1w[(size_t)(((half * 4 + g) * 16 + kk) * 512)];
#pragma unroll
                for (int g = 0; g < 4; g++) {
                    acc[0][g] = MFMA_BF16(a0, b[g], acc[0][g]);
                    acc[1][g] = MFMA_BF16(a1, b[g], acc[1][g]);
                }
            }
            if (half == 0) { EPIB(0); } else { EPIB(1); }
        }
        {
            const unsigned short* h1t = lds + 16384 + (i & 1) * 8192;
            float p0 = 0.f, p1 = 0.f;
#pragma unroll
            for (int q = 0; q < 2; q++) {
                int col0 = pseg * 16 + q * 8;
                short8 hv = *(const short8*)&h1t[prow * 256 + (col0 ^ psw)];
#pragma unroll
                for (int e = 0; e < 8; e++) {
                    float h = bf2f((unsigned short)hv[e]);
                    p0 += h * wopl[col0 + e];
                    p1 += h * wopl[256 + col0 + e];
                }
            }
#pragma unroll
            for (int sfl = 1; sfl < 16; sfl <<= 1) {
                p0 += __shfl_xor(p0, sfl, 64);
                p1 += __shfl_xor(p1, sfl, 64);
            }
            if (pseg == 0) {
                int grow = blk * 32 + prow;
                out_final[((size_t)grow * TT + 28) * 2 + 0] = p0 + b_op[0];
                out_final[((size_t)grow * TT + 28) * 2 + 1] = p1 + b_op[1];
            }
        }
    }
    __syncthreads();

    // ================= i = 31 : proj(29) =================
    {
        const unsigned short* h1t = lds + 16384 + (31 & 1) * 8192;
        float p0 = 0.f, p1 = 0.f;
#pragma unroll
        for (int q = 0; q < 2; q++) {
            int col0 = pseg * 16 + q * 8;
            short8 hv = *(const short8*)&h1t[prow * 256 + (col0 ^ psw)];
#pragma unroll
            for (int e = 0; e < 8; e++) {
                float h = bf2f((unsigned short)hv[e]);
                p0 += h * wopl[col0 + e];
                p1 += h * wopl[256 + col0 + e];
            }
        }
#pragma unroll
        for (int sfl = 1; sfl < 16; sfl <<= 1) {
            p0 += __shfl_xor(p0, sfl, 64);
            p1 += __shfl_xor(p1, sfl, 64);
        }
        if (pseg == 0) {
            int grow = blk * 32 + prow;
            out_final[((size_t)grow * TT + 29) * 2 + 0] = p0 + b_op[0];
            out_final[((size_t)grow * TT + 29) * 2 + 1] = p1 + b_op[1];
        }
    }
}

// ---------------- host ----------------
extern "C" void kernel_launch(void* const* d_in, const int* in_sizes, int n_in,
                              void* d_out, int out_size, void* d_ws, size_t ws_size,
                              hipStream_t stream)
{
    const float* obs    = (const float*)d_in[0];
    const float* lane   = (const float*)d_in[1];
    const float* ds     = (const float*)d_in[3];
    const float* W_hid  = (const float*)d_in[4];
    const float* b_hid  = (const float*)d_in[5];
    const float* W_ep   = (const float*)d_in[6];
    const float* b_ep   = (const float*)d_in[7];
    const float* W_conf = (const float*)d_in[8];
    const float* b_conf = (const float*)d_in[9];
    const float* W_ih0  = (const float*)d_in[10];
    const float* W_hh0  = (const float*)d_in[11];
    const float* b_ih0  = (const float*)d_in[12];
    const float* b_hh0  = (const float*)d_in[13];
    const float* W_ih1  = (const float*)d_in[14];
    const float* W_hh1  = (const float*)d_in[15];
    const float* b_ih1  = (const float*)d_in[16];
    const float* b_hh1  = (const float*)d_in[17];
    const float* W_op   = (const float*)d_in[18];
    const float* b_op   = (const float*)d_in[19];

    float* out_final = (float*)d_out;           // [6144*30*2]
    float* out_conf  = out_final + 368640;      // [6144]
    float* out_ep    = out_conf + 6144;         // [6144*2]

    char* ws = (char*)d_ws;
    size_t off = 0;
    auto alloc = [&](size_t bytes) -> void* {
        void* p = ws + off;
        off += (bytes + 255) & ~(size_t)255;
        return p;
    };
    unsigned short* Whid_b = (unsigned short*)alloc(65536 * 2);
    unsigned short* Wih0_b = (unsigned short*)alloc(262144 * 2);
    unsigned short* Wp0    = (unsigned short*)alloc(262144 * 2);
    unsigned short* Wp1    = (unsigned short*)alloc(524288 * 2);
    float*          biasC  = (float*)alloc(1024 * 4);
    unsigned short* Wcomb  = (unsigned short*)alloc((size_t)786432 * 2);
    unsigned short* comb_b = (unsigned short*)alloc(1572864 * 2);
    unsigned short* hid_b  = (unsigned short*)alloc(1572864 * 2);
    float* ep_buf = (float*)alloc(12288 * 4);
    u16x4* gxs4   = (u16x4*)alloc((size_t)1572864 * 8);

    cvt_weights<<<4356, 256, 0, stream>>>(W_hid, W_ih0, W_hh0, W_ih1, W_hh1,
                                          b_ih1, b_hh1,
                                          Whid_b, Wih0_b, Wp0, Wp1, biasC);
    pack_comb<<<3072, 256, 0, stream>>>(Wp0, Wp1, Wcomb);
    build_combined<<<6144, 256, 0, stream>>>(obs, lane, ds, comb_b);
    gemm_hidden<<<96, 256, 0, stream>>>(comb_b, Whid_b, b_hid, hid_b);
    head_kernel<<<24, 256, 0, stream>>>(hid_b, W_ep, b_ep, W_conf, b_conf,
                                        out_conf, out_ep, ep_buf);
    dim3 g2(96, 4);
    gemm_gx0<<<g2, 256, 0, stream>>>(hid_b, Wih0_b, W_ih0, b_ih0, b_hh0, ep_buf, gxs4);

    lstm_persistent<<<192, 512, 0, stream>>>(Wp0, Wp1, Wcomb, gxs4, biasC,
                                             W_op, b_op, out_final);
}